// Round 1
// baseline (1649.610 us; speedup 1.0000x reference)
//
#include <hip/hip_runtime.h>
#include <hip/hip_bf16.h>

// Problem constants
#define BB 8
#define TT 1024
#define CC 512
#define HH 8
#define EE 256            // head dim (= C/2)
#define MM (BB*TT)        // 8192 rows
#define HE (HH*EE)        // 2048

using short8   = __attribute__((ext_vector_type(8))) short;
using ushort4v = __attribute__((ext_vector_type(4))) unsigned short;

__device__ __forceinline__ float bf2f(unsigned short u) {
  union { float f; unsigned int i; } v; v.i = ((unsigned int)u) << 16; return v.f;
}
__device__ __forceinline__ unsigned short f2bf(float f) {
  union { float f; unsigned int i; } v; v.f = f;
  unsigned int r = v.i + 0x7FFFu + ((v.i >> 16) & 1u);  // RNE
  return (unsigned short)(r >> 16);
}

// ---------------------------------------------------------------------------
// Kernel 1: copy x1 (cols 0..255) straight to output (cols 0..255)
// ---------------------------------------------------------------------------
__global__ __launch_bounds__(256) void copy_x1_kernel(const float* __restrict__ x,
                                                      float* __restrict__ out) {
  int idx = blockIdx.x * 256 + threadIdx.x;     // one float4 per thread
  int row = idx >> 6;                           // 64 float4 per row-half
  int c4  = (idx & 63) * 4;
  *reinterpret_cast<float4*>(&out[(size_t)row * CC + c4]) =
      *reinterpret_cast<const float4*>(&x[(size_t)row * CC + c4]);
}

// ---------------------------------------------------------------------------
// Kernel 2: QKV projection GEMM.  out[m][n] = scale * sum_k x[m][k] * W[n][k]
//   x: [8192 x 512] (use first 256 cols), W: [2048 x 256], out: bf16 [8192 x 2048]
//   64x64 tile, BK=32, 256 threads, 4x4 micro-tile.
// ---------------------------------------------------------------------------
__global__ __launch_bounds__(256) void qkv_gemm_kernel(const float* __restrict__ x,
                                                       const float* __restrict__ W,
                                                       unsigned short* __restrict__ out,
                                                       float scale) {
  __shared__ float As[32][68];   // [k][m], pad to keep 16B row alignment
  __shared__ float Bs[32][68];   // [k][n]
  const int tid = threadIdx.x;
  const int m0 = blockIdx.y * 64;
  const int n0 = blockIdx.x * 64;
  const int tm = (tid >> 4) * 4;   // 4 rows
  const int tn = (tid & 15) * 4;   // 4 cols (consecutive lanes -> consecutive cols)
  float acc[4][4] = {};

  for (int k0 = 0; k0 < EE; k0 += 32) {
#pragma unroll
    for (int it = 0; it < 2; ++it) {
      int slot = it * 256 + tid;
      int row = slot >> 3, c4 = (slot & 7) * 4;
      float4 a = *reinterpret_cast<const float4*>(&x[(size_t)(m0 + row) * CC + k0 + c4]);
      As[c4 + 0][row] = a.x; As[c4 + 1][row] = a.y; As[c4 + 2][row] = a.z; As[c4 + 3][row] = a.w;
      float4 b = *reinterpret_cast<const float4*>(&W[(size_t)(n0 + row) * EE + k0 + c4]);
      Bs[c4 + 0][row] = b.x; Bs[c4 + 1][row] = b.y; Bs[c4 + 2][row] = b.z; Bs[c4 + 3][row] = b.w;
    }
    __syncthreads();
#pragma unroll
    for (int kk = 0; kk < 32; ++kk) {
      const float4 a4 = *reinterpret_cast<const float4*>(&As[kk][tm]);
      const float4 b4 = *reinterpret_cast<const float4*>(&Bs[kk][tn]);
      const float av[4] = {a4.x, a4.y, a4.z, a4.w};
      const float bv[4] = {b4.x, b4.y, b4.z, b4.w};
#pragma unroll
      for (int i = 0; i < 4; ++i)
#pragma unroll
        for (int j = 0; j < 4; ++j)
          acc[i][j] = fmaf(av[i], bv[j], acc[i][j]);
    }
    __syncthreads();
  }

#pragma unroll
  for (int i = 0; i < 4; ++i) {
    ushort4v o;
#pragma unroll
    for (int j = 0; j < 4; ++j) o[j] = f2bf(acc[i][j] * scale);
    *reinterpret_cast<ushort4v*>(&out[(size_t)(m0 + tm + i) * HE + n0 + tn]) = o;
  }
}

// ---------------------------------------------------------------------------
// Kernel 3: attention.  One block = one (b,h) and 64 query rows.
//   Loops over 64-row K/V tiles: S = QK^T, P = exp(S) (no max-sub needed: |S|<~2),
//   O += P*V, l += rowsum(P).  Final: O/l -> bf16 attn_out.
//   512 threads. Thread owns 4 q-rows {rg+16i} x (score: 2 k-cols / PV: 8 v-cols).
// ---------------------------------------------------------------------------
#define QBLK 64
#define SBLK 64

__global__ __launch_bounds__(512) void attn_kernel(const unsigned short* __restrict__ qg,
                                                   const unsigned short* __restrict__ kg,
                                                   const unsigned short* __restrict__ vg,
                                                   unsigned short* __restrict__ og) {
  __shared__ unsigned short Qs[QBLK][264];  // bf16, +8 pad (keeps 16B align, strided rows -> <=2-way)
  __shared__ unsigned short Ks[SBLK][264];
  __shared__ unsigned short Vs[SBLK][264];
  __shared__ float Ss[QBLK][65];            // exp(scores)
  __shared__ float lsum[QBLK];

  const int tid = threadIdx.x;
  const int bh = blockIdx.y;
  const int b = bh >> 3, h = bh & 7;
  const int t0 = blockIdx.x * QBLK;
  const size_t base = (size_t)b * TT * HE + (size_t)h * EE;

  // load Q tile (64 x 256 bf16)
#pragma unroll
  for (int it = 0; it < 4; ++it) {
    int slot = it * 512 + tid;
    int r = slot >> 5, c8 = (slot & 31) * 8;
    *reinterpret_cast<short8*>(&Qs[r][c8]) =
        *reinterpret_cast<const short8*>(&qg[base + (size_t)(t0 + r) * HE + c8]);
  }
  if (tid < QBLK) lsum[tid] = 0.f;

  const int rg = tid >> 5;   // 0..15: rows {rg, rg+16, rg+32, rg+48}
  const int cg = tid & 31;   // 0..31
  float O[4][8] = {};

  for (int s0 = 0; s0 < TT; s0 += SBLK) {
    __syncthreads();  // previous PV done before overwriting K/V
#pragma unroll
    for (int it = 0; it < 4; ++it) {
      int slot = it * 512 + tid;
      int r = slot >> 5, c8 = (slot & 31) * 8;
      *reinterpret_cast<short8*>(&Ks[r][c8]) =
          *reinterpret_cast<const short8*>(&kg[base + (size_t)(s0 + r) * HE + c8]);
      *reinterpret_cast<short8*>(&Vs[r][c8]) =
          *reinterpret_cast<const short8*>(&vg[base + (size_t)(s0 + r) * HE + c8]);
    }
    __syncthreads();

    // scores: 4 q-rows x 2 k-cols per thread, dot over 256
    float acc[4][2] = {};
    for (int ec = 0; ec < EE; ec += 8) {
      float qv[4][8];
#pragma unroll
      for (int i = 0; i < 4; ++i) {
        short8 q8 = *reinterpret_cast<const short8*>(&Qs[rg + 16 * i][ec]);
#pragma unroll
        for (int e = 0; e < 8; ++e) qv[i][e] = bf2f((unsigned short)q8[e]);
      }
#pragma unroll
      for (int j = 0; j < 2; ++j) {
        short8 k8 = *reinterpret_cast<const short8*>(&Ks[cg + 32 * j][ec]);
        float kv[8];
#pragma unroll
        for (int e = 0; e < 8; ++e) kv[e] = bf2f((unsigned short)k8[e]);
#pragma unroll
        for (int i = 0; i < 4; ++i)
#pragma unroll
          for (int e = 0; e < 8; ++e)
            acc[i][j] = fmaf(qv[i][e], kv[e], acc[i][j]);
      }
    }

    // exp + row partial sums (reduce over the 32 cg lanes of each wave half)
    float part[4];
#pragma unroll
    for (int i = 0; i < 4; ++i) {
      float e0 = __expf(acc[i][0]);
      float e1 = __expf(acc[i][1]);
      Ss[rg + 16 * i][cg] = e0;
      Ss[rg + 16 * i][cg + 32] = e1;
      part[i] = e0 + e1;
    }
#pragma unroll
    for (int off = 1; off < 32; off <<= 1) {
#pragma unroll
      for (int i = 0; i < 4; ++i) part[i] += __shfl_xor(part[i], off, 64);
    }
    if (cg == 0) {
#pragma unroll
      for (int i = 0; i < 4; ++i) lsum[rg + 16 * i] += part[i];
    }
    __syncthreads();

    // PV: O[i][0..7] += Ss[row][s] * V[s][cg*8..+7]
#pragma unroll 2
    for (int s = 0; s < SBLK; ++s) {
      float p[4];
#pragma unroll
      for (int i = 0; i < 4; ++i) p[i] = Ss[rg + 16 * i][s];
      short8 v8 = *reinterpret_cast<const short8*>(&Vs[s][cg * 8]);
      float vf[8];
#pragma unroll
      for (int e = 0; e < 8; ++e) vf[e] = bf2f((unsigned short)v8[e]);
#pragma unroll
      for (int i = 0; i < 4; ++i)
#pragma unroll
        for (int e = 0; e < 8; ++e)
          O[i][e] = fmaf(p[i], vf[e], O[i][e]);
    }
  }
  __syncthreads();

  // normalize + store bf16
#pragma unroll
  for (int i = 0; i < 4; ++i) {
    float inv = 1.0f / lsum[rg + 16 * i];
    short8 o8;
#pragma unroll
    for (int e = 0; e < 8; ++e) o8[e] = (short)f2bf(O[i][e] * inv);
    *reinterpret_cast<short8*>(&og[base + (size_t)(t0 + rg + 16 * i) * HE + cg * 8]) = o8;
  }
}

// ---------------------------------------------------------------------------
// Kernel 4: output projection + bias + residual into out cols 256..511
//   unified[m][n] = sum_o ao[m][o]*Wu[n][o];  out[m][256+n] = x[m][256+n] + unified + bu[n]
//   ao: bf16 [8192 x 2048], Wu: [256 x 2048]
// ---------------------------------------------------------------------------
__global__ __launch_bounds__(256) void proj_kernel(const unsigned short* __restrict__ ao,
                                                   const float* __restrict__ Wu,
                                                   const float* __restrict__ bu,
                                                   const float* __restrict__ x,
                                                   float* __restrict__ out) {
  __shared__ float As[32][68];   // [k][m]
  __shared__ float Bs[32][68];   // [k][n]
  const int tid = threadIdx.x;
  const int m0 = blockIdx.y * 64;
  const int n0 = blockIdx.x * 64;
  const int tm = (tid >> 4) * 4;
  const int tn = (tid & 15) * 4;
  float acc[4][4] = {};

  for (int k0 = 0; k0 < HE; k0 += 32) {
    {
      int row = tid >> 2, c8 = (tid & 3) * 8;   // 64 rows x 32 k of bf16 A
      short8 a8 = *reinterpret_cast<const short8*>(&ao[(size_t)(m0 + row) * HE + k0 + c8]);
#pragma unroll
      for (int e = 0; e < 8; ++e) As[c8 + e][row] = bf2f((unsigned short)a8[e]);
#pragma unroll
      for (int it = 0; it < 2; ++it) {
        int slot = it * 256 + tid;
        int brow = slot >> 3, c4 = (slot & 7) * 4;
        float4 bvv = *reinterpret_cast<const float4*>(&Wu[(size_t)(n0 + brow) * HE + k0 + c4]);
        Bs[c4 + 0][brow] = bvv.x; Bs[c4 + 1][brow] = bvv.y;
        Bs[c4 + 2][brow] = bvv.z; Bs[c4 + 3][brow] = bvv.w;
      }
    }
    __syncthreads();
#pragma unroll
    for (int kk = 0; kk < 32; ++kk) {
      const float4 a4 = *reinterpret_cast<const float4*>(&As[kk][tm]);
      const float4 b4 = *reinterpret_cast<const float4*>(&Bs[kk][tn]);
      const float av[4] = {a4.x, a4.y, a4.z, a4.w};
      const float bv4[4] = {b4.x, b4.y, b4.z, b4.w};
#pragma unroll
      for (int i = 0; i < 4; ++i)
#pragma unroll
        for (int j = 0; j < 4; ++j)
          acc[i][j] = fmaf(av[i], bv4[j], acc[i][j]);
    }
    __syncthreads();
  }

#pragma unroll
  for (int i = 0; i < 4; ++i) {
    int m = m0 + tm + i;
    float4 x2 = *reinterpret_cast<const float4*>(&x[(size_t)m * CC + EE + n0 + tn]);
    float4 bb = *reinterpret_cast<const float4*>(&bu[n0 + tn]);
    float4 o;
    o.x = acc[i][0] + x2.x + bb.x;
    o.y = acc[i][1] + x2.y + bb.y;
    o.z = acc[i][2] + x2.z + bb.z;
    o.w = acc[i][3] + x2.w + bb.w;
    *reinterpret_cast<float4*>(&out[(size_t)m * CC + EE + n0 + tn]) = o;
  }
}

// ---------------------------------------------------------------------------
extern "C" void kernel_launch(void* const* d_in, const int* in_sizes, int n_in,
                              void* d_out, int out_size, void* d_ws, size_t ws_size,
                              hipStream_t stream) {
  const float* x  = (const float*)d_in[0];
  const float* Wq = (const float*)d_in[1];
  const float* Wk = (const float*)d_in[2];
  const float* Wv = (const float*)d_in[3];
  const float* Wu = (const float*)d_in[4];
  const float* bu = (const float*)d_in[5];
  float* out = (float*)d_out;

  // workspace: q, k, v, attn_out as bf16 [8192 x 2048] each = 32 MB each (128 MB total)
  unsigned short* q  = (unsigned short*)d_ws;
  unsigned short* k  = q + (size_t)MM * HE;
  unsigned short* v  = k + (size_t)MM * HE;
  unsigned short* ao = v + (size_t)MM * HE;

  const float scale = 0.25f;   // E^-0.25 = 256^-0.25

  copy_x1_kernel<<<dim3(2048), dim3(256), 0, stream>>>(x, out);

  dim3 gq(HE / 64, MM / 64);   // (32, 128)
  qkv_gemm_kernel<<<gq, dim3(256), 0, stream>>>(x, Wq, q, scale);
  qkv_gemm_kernel<<<gq, dim3(256), 0, stream>>>(x, Wk, k, scale);
  qkv_gemm_kernel<<<gq, dim3(256), 0, stream>>>(x, Wv, v, 1.0f);

  attn_kernel<<<dim3(TT / QBLK, BB * HH), dim3(512), 0, stream>>>(q, k, v, ao);

  proj_kernel<<<dim3(EE / 64, MM / 64), dim3(256), 0, stream>>>(ao, Wu, bu, x, out);
}

// Round 2
// 706.771 us; speedup vs baseline: 2.3340x; 2.3340x over previous
//
#include <hip/hip_runtime.h>
#include <hip/hip_bf16.h>

// Problem constants
#define BB 8
#define TT 1024
#define CC 512
#define HH 8
#define EE 256            // head dim (= C/2)
#define MM (BB*TT)        // 8192 rows
#define HE (HH*EE)        // 2048

using short8 = __attribute__((ext_vector_type(8))) short;
using f32x16 = __attribute__((ext_vector_type(16))) float;
using uint2v = __attribute__((ext_vector_type(2))) unsigned int;
using ushort4v = __attribute__((ext_vector_type(4))) unsigned short;

__device__ __forceinline__ float bf2f(unsigned short u) {
  union { float f; unsigned int i; } v; v.i = ((unsigned int)u) << 16; return v.f;
}
__device__ __forceinline__ unsigned short f2bf(float f) {
  union { float f; unsigned int i; } v; v.f = f;
  unsigned int r = v.i + 0x7FFFu + ((v.i >> 16) & 1u);  // RNE
  return (unsigned short)(r >> 16);
}
__device__ __forceinline__ unsigned int pk_bf16(float lo, float hi) {
  unsigned int r;
  asm("v_cvt_pk_bf16_f32 %0, %1, %2" : "=v"(r) : "v"(lo), "v"(hi));
  return r;
}

// ---------------------------------------------------------------------------
// Kernel 1: copy x1 (cols 0..255) straight to output (cols 0..255)
// ---------------------------------------------------------------------------
__global__ __launch_bounds__(256) void copy_x1_kernel(const float* __restrict__ x,
                                                      float* __restrict__ out) {
  int idx = blockIdx.x * 256 + threadIdx.x;
  int row = idx >> 6;
  int c4  = (idx & 63) * 4;
  *reinterpret_cast<float4*>(&out[(size_t)row * CC + c4]) =
      *reinterpret_cast<const float4*>(&x[(size_t)row * CC + c4]);
}

// ---------------------------------------------------------------------------
// Kernel 2: QKV projection GEMM.  out[m][n] = scale * sum_k x[m][k] * W[n][k]
//   vt_mode=1: write transposed layout vt[(b*8+h)*256 + e][t]  (for V)
// ---------------------------------------------------------------------------
__global__ __launch_bounds__(256) void qkv_gemm_kernel(const float* __restrict__ x,
                                                       const float* __restrict__ W,
                                                       unsigned short* __restrict__ out,
                                                       float scale, int vt_mode) {
  __shared__ float As[32][68];
  __shared__ float Bs[32][68];
  const int tid = threadIdx.x;
  const int m0 = blockIdx.y * 64;
  const int n0 = blockIdx.x * 64;
  const int tm = (tid >> 4) * 4;
  const int tn = (tid & 15) * 4;
  float acc[4][4] = {};

  for (int k0 = 0; k0 < EE; k0 += 32) {
#pragma unroll
    for (int it = 0; it < 2; ++it) {
      int slot = it * 256 + tid;
      int row = slot >> 3, c4 = (slot & 7) * 4;
      float4 a = *reinterpret_cast<const float4*>(&x[(size_t)(m0 + row) * CC + k0 + c4]);
      As[c4 + 0][row] = a.x; As[c4 + 1][row] = a.y; As[c4 + 2][row] = a.z; As[c4 + 3][row] = a.w;
      float4 b = *reinterpret_cast<const float4*>(&W[(size_t)(n0 + row) * EE + k0 + c4]);
      Bs[c4 + 0][row] = b.x; Bs[c4 + 1][row] = b.y; Bs[c4 + 2][row] = b.z; Bs[c4 + 3][row] = b.w;
    }
    __syncthreads();
#pragma unroll
    for (int kk = 0; kk < 32; ++kk) {
      const float4 a4 = *reinterpret_cast<const float4*>(&As[kk][tm]);
      const float4 b4 = *reinterpret_cast<const float4*>(&Bs[kk][tn]);
      const float av[4] = {a4.x, a4.y, a4.z, a4.w};
      const float bv[4] = {b4.x, b4.y, b4.z, b4.w};
#pragma unroll
      for (int i = 0; i < 4; ++i)
#pragma unroll
        for (int j = 0; j < 4; ++j)
          acc[i][j] = fmaf(av[i], bv[j], acc[i][j]);
    }
    __syncthreads();
  }

  if (!vt_mode) {
#pragma unroll
    for (int i = 0; i < 4; ++i) {
      ushort4v o;
#pragma unroll
      for (int j = 0; j < 4; ++j) o[j] = f2bf(acc[i][j] * scale);
      *reinterpret_cast<ushort4v*>(&out[(size_t)(m0 + tm + i) * HE + n0 + tn]) = o;
    }
  } else {
    // vt[(b*8 + h)*256 + e][t] ;  b=m>>10, t=m&1023, h=n>>8, e=n&255
#pragma unroll
    for (int i = 0; i < 4; ++i) {
      int m = m0 + tm + i;
      size_t rowbase = (size_t)(m >> 10) * 2048;
      int t = m & 1023;
#pragma unroll
      for (int j = 0; j < 4; ++j) {
        int n = n0 + tn + j;
        out[(rowbase + (size_t)(n >> 8) * 256 + (n & 255)) * TT + t] = f2bf(acc[i][j] * scale);
      }
    }
  }
}

// ---------------------------------------------------------------------------
// Kernel 3: MFMA attention.  256 threads = 4 waves (wq in {0,1}, ws in {0,1}).
//   QBLK=64 q rows per block, SBLK=64 keys per iteration.
//   Swapped QK^T: S^T = mfma(A=K, B=Q) -> lane holds P-row for q = lane&31.
//   P -> PV A-frags via v_cvt_pk_bf16_f32 + permlane32_swap (no LDS for P).
//   Wave accumulates O_partial[32 q][256 e] over its 32-s half; ws pair
//   combined through LDS at the end.  No max-subtraction (|S| < ~1).
// ---------------------------------------------------------------------------
#define KSTR 264
#define VSTR 72
#define OSTR 264
#define SM_KS 0
#define SM_VT 33792
#define SM_LP 70656
#define SM_TOT 71168

__global__ __launch_bounds__(256, 2) void attn_kernel(const unsigned short* __restrict__ qg,
                                                      const unsigned short* __restrict__ kg,
                                                      const unsigned short* __restrict__ vtg,
                                                      unsigned short* __restrict__ og) {
  __shared__ char smem[SM_TOT];
  unsigned short* Ks = (unsigned short*)(smem + SM_KS);   // [64][264]
  unsigned short* Vt = (unsigned short*)(smem + SM_VT);   // [256][72]
  float* lpart = (float*)(smem + SM_LP);                  // [2][64]
  float* Olds = (float*)smem;                             // epilogue reuse [2][32][264]

  const int tid = threadIdx.x;
  const int lane = tid & 63;
  const int wid = tid >> 6;
  const int wq = wid >> 1, ws = wid & 1;
  const int lo = lane & 31, hi = lane >> 5;

  // XCD-aware bijective swizzle: 16 t-tiles of each (b,h) on one XCD
  int logical = (blockIdx.x & 7) * 128 + (blockIdx.x >> 3);
  const int bh = logical >> 4;
  const int ttile = logical & 15;
  const int b = bh >> 3, h = bh & 7;
  const int t0 = ttile * 64;
  const size_t qkbase = (size_t)b * TT * HE + (size_t)h * EE;
  const size_t vtbase = (size_t)bh * EE * TT;

  // hoist Q fragments (B-operand of swapped QK^T): rows of Q, 16B each
  short8 qf[16];
  {
    const unsigned short* qrow = qg + qkbase + (size_t)(t0 + 32 * wq + lo) * HE + hi * 8;
#pragma unroll
    for (int ks = 0; ks < 16; ++ks)
      qf[ks] = *reinterpret_cast<const short8*>(qrow + ks * 16);
  }

  f32x16 Oacc[8];
#pragma unroll
  for (int et = 0; et < 8; ++et)
#pragma unroll
    for (int r = 0; r < 16; ++r) Oacc[et][r] = 0.f;
  float lacc = 0.f;

  for (int s0 = 0; s0 < TT; s0 += 64) {
    __syncthreads();   // previous PV done before overwriting K/Vt
#pragma unroll
    for (int it = 0; it < 8; ++it) {
      int slot = it * 256 + tid;
      int r = slot >> 5, c8 = (slot & 31) * 8;
      *reinterpret_cast<short8*>(&Ks[r * KSTR + c8]) =
          *reinterpret_cast<const short8*>(&kg[qkbase + (size_t)(s0 + r) * HE + c8]);
    }
#pragma unroll
    for (int it = 0; it < 8; ++it) {
      int slot = it * 256 + tid;
      int e = slot >> 3, s8 = (slot & 7) * 8;
      *reinterpret_cast<short8*>(&Vt[e * VSTR + s8]) =
          *reinterpret_cast<const short8*>(&vtg[vtbase + (size_t)e * TT + s0 + s8]);
    }
    __syncthreads();

    // ---- QK^T (swapped): S^T[32 s x 32 q], acc over E=256 (16 K-steps)
    f32x16 sacc;
#pragma unroll
    for (int r = 0; r < 16; ++r) sacc[r] = 0.f;
#pragma unroll
    for (int ks = 0; ks < 16; ++ks) {
      short8 kf = *reinterpret_cast<const short8*>(&Ks[(32 * ws + lo) * KSTR + ks * 16 + hi * 8]);
      sacc = __builtin_amdgcn_mfma_f32_32x32x16_bf16(kf, qf[ks], sacc, 0, 0, 0);
    }

    // ---- softmax numerator in registers; lane owns q-row (lo), 16 s-values
    float p[16];
#pragma unroll
    for (int r = 0; r < 16; ++r) { p[r] = __expf(sacc[r]); lacc += p[r]; }

    // ---- pack P into PV A-fragments: cvt_pk + permlane32_swap
    short8 pa[2];
#pragma unroll
    for (int ksl = 0; ksl < 2; ++ksl) {
      unsigned int a1 = pk_bf16(p[8 * ksl + 0], p[8 * ksl + 1]);
      unsigned int a2 = pk_bf16(p[8 * ksl + 2], p[8 * ksl + 3]);
      unsigned int b1 = pk_bf16(p[8 * ksl + 4], p[8 * ksl + 5]);
      unsigned int b2 = pk_bf16(p[8 * ksl + 6], p[8 * ksl + 7]);
      uint2v r1 = __builtin_amdgcn_permlane32_swap(a1, b1, false, false);
      uint2v r2 = __builtin_amdgcn_permlane32_swap(a2, b2, false, false);
      union { unsigned int u[4]; short8 v; } uu;
      uu.u[0] = r1[0]; uu.u[1] = r2[0]; uu.u[2] = r1[1]; uu.u[3] = r2[1];
      pa[ksl] = uu.v;
    }

    // ---- PV: O_partial[32 q][256 e] += P[32 q][32 s] * V[32 s][256 e]
#pragma unroll
    for (int et = 0; et < 8; ++et) {
#pragma unroll
      for (int ksl = 0; ksl < 2; ++ksl) {
        short8 vf = *reinterpret_cast<const short8*>(
            &Vt[(et * 32 + lo) * VSTR + 32 * ws + 16 * ksl + hi * 8]);
        Oacc[et] = __builtin_amdgcn_mfma_f32_32x32x16_bf16(pa[ksl], vf, Oacc[et], 0, 0, 0);
      }
    }
  }

  // ---- epilogue: combine hi halves of lacc, then ws pairs via LDS
  lacc += __shfl_xor(lacc, 32);
  if (hi == 0) lpart[ws * 64 + 32 * wq + lo] = lacc;
  __syncthreads();   // all PV done; safe to reuse Ks/Vt as Olds

  if (ws == 1) {
    float* dst = Olds + wq * (32 * OSTR);
#pragma unroll
    for (int reg = 0; reg < 16; ++reg) {
      int rr = (reg & 3) + 8 * (reg >> 2) + 4 * hi;
#pragma unroll
      for (int et = 0; et < 8; ++et)
        dst[rr * OSTR + et * 32 + lo] = Oacc[et][reg];
    }
  }
  __syncthreads();
  if (ws == 0) {
    const float* src = Olds + wq * (32 * OSTR);
#pragma unroll
    for (int reg = 0; reg < 16; ++reg) {
      int rr = (reg & 3) + 8 * (reg >> 2) + 4 * hi;
      float inv = 1.0f / (lpart[32 * wq + rr] + lpart[64 + 32 * wq + rr]);
      int t = t0 + 32 * wq + rr;
#pragma unroll
      for (int et = 0; et < 8; ++et) {
        float o = (Oacc[et][reg] + src[rr * OSTR + et * 32 + lo]) * inv;
        og[qkbase + (size_t)t * HE + et * 32 + lo] = f2bf(o);
      }
    }
  }
}

// ---------------------------------------------------------------------------
// Kernel 4: output projection + bias + residual into out cols 256..511
// ---------------------------------------------------------------------------
__global__ __launch_bounds__(256) void proj_kernel(const unsigned short* __restrict__ ao,
                                                   const float* __restrict__ Wu,
                                                   const float* __restrict__ bu,
                                                   const float* __restrict__ x,
                                                   float* __restrict__ out) {
  __shared__ float As[32][68];
  __shared__ float Bs[32][68];
  const int tid = threadIdx.x;
  const int m0 = blockIdx.y * 64;
  const int n0 = blockIdx.x * 64;
  const int tm = (tid >> 4) * 4;
  const int tn = (tid & 15) * 4;
  float acc[4][4] = {};

  for (int k0 = 0; k0 < HE; k0 += 32) {
    {
      int row = tid >> 2, c8 = (tid & 3) * 8;
      short8 a8 = *reinterpret_cast<const short8*>(&ao[(size_t)(m0 + row) * HE + k0 + c8]);
#pragma unroll
      for (int e = 0; e < 8; ++e) As[c8 + e][row] = bf2f((unsigned short)a8[e]);
#pragma unroll
      for (int it = 0; it < 2; ++it) {
        int slot = it * 256 + tid;
        int brow = slot >> 3, c4 = (slot & 7) * 4;
        float4 bvv = *reinterpret_cast<const float4*>(&Wu[(size_t)(n0 + brow) * HE + k0 + c4]);
        Bs[c4 + 0][brow] = bvv.x; Bs[c4 + 1][brow] = bvv.y;
        Bs[c4 + 2][brow] = bvv.z; Bs[c4 + 3][brow] = bvv.w;
      }
    }
    __syncthreads();
#pragma unroll
    for (int kk = 0; kk < 32; ++kk) {
      const float4 a4 = *reinterpret_cast<const float4*>(&As[kk][tm]);
      const float4 b4 = *reinterpret_cast<const float4*>(&Bs[kk][tn]);
      const float av[4] = {a4.x, a4.y, a4.z, a4.w};
      const float bv4[4] = {b4.x, b4.y, b4.z, b4.w};
#pragma unroll
      for (int i = 0; i < 4; ++i)
#pragma unroll
        for (int j = 0; j < 4; ++j)
          acc[i][j] = fmaf(av[i], bv4[j], acc[i][j]);
    }
    __syncthreads();
  }

#pragma unroll
  for (int i = 0; i < 4; ++i) {
    int m = m0 + tm + i;
    float4 x2 = *reinterpret_cast<const float4*>(&x[(size_t)m * CC + EE + n0 + tn]);
    float4 bb = *reinterpret_cast<const float4*>(&bu[n0 + tn]);
    float4 o;
    o.x = acc[i][0] + x2.x + bb.x;
    o.y = acc[i][1] + x2.y + bb.y;
    o.z = acc[i][2] + x2.z + bb.z;
    o.w = acc[i][3] + x2.w + bb.w;
    *reinterpret_cast<float4*>(&out[(size_t)m * CC + EE + n0 + tn]) = o;
  }
}

// ---------------------------------------------------------------------------
extern "C" void kernel_launch(void* const* d_in, const int* in_sizes, int n_in,
                              void* d_out, int out_size, void* d_ws, size_t ws_size,
                              hipStream_t stream) {
  const float* x  = (const float*)d_in[0];
  const float* Wq = (const float*)d_in[1];
  const float* Wk = (const float*)d_in[2];
  const float* Wv = (const float*)d_in[3];
  const float* Wu = (const float*)d_in[4];
  const float* bu = (const float*)d_in[5];
  float* out = (float*)d_out;

  unsigned short* q  = (unsigned short*)d_ws;
  unsigned short* k  = q + (size_t)MM * HE;
  unsigned short* vt = k + (size_t)MM * HE;
  unsigned short* ao = vt + (size_t)MM * HE;

  const float scale = 0.25f;   // 256^-0.25

  copy_x1_kernel<<<dim3(2048), dim3(256), 0, stream>>>(x, out);

  dim3 gq(HE / 64, MM / 64);
  qkv_gemm_kernel<<<gq, dim3(256), 0, stream>>>(x, Wq, q, scale, 0);
  qkv_gemm_kernel<<<gq, dim3(256), 0, stream>>>(x, Wk, k, scale, 0);
  qkv_gemm_kernel<<<gq, dim3(256), 0, stream>>>(x, Wv, vt, 1.0f, 1);

  attn_kernel<<<dim3(1024), dim3(256), 0, stream>>>(q, k, vt, ao);

  proj_kernel<<<dim3(EE / 64, MM / 64), dim3(256), 0, stream>>>(ao, Wu, bu, x, out);
}

// Round 3
// 260.373 us; speedup vs baseline: 6.3356x; 2.7145x over previous
//
#include <hip/hip_runtime.h>
#include <hip/hip_bf16.h>

// Problem constants
#define BB 8
#define TT 1024
#define CC 512
#define HH 8
#define EE 256            // head dim (= C/2)
#define MM (BB*TT)        // 8192 rows
#define HE (HH*EE)        // 2048

using short8 = __attribute__((ext_vector_type(8))) short;
using f32x16 = __attribute__((ext_vector_type(16))) float;
using uint2v = __attribute__((ext_vector_type(2))) unsigned int;

__device__ __forceinline__ float bf2f(unsigned short u) {
  union { float f; unsigned int i; } v; v.i = ((unsigned int)u) << 16; return v.f;
}
__device__ __forceinline__ unsigned short f2bf(float f) {
  union { float f; unsigned int i; } v; v.f = f;
  unsigned int r = v.i + 0x7FFFu + ((v.i >> 16) & 1u);  // RNE
  return (unsigned short)(r >> 16);
}
__device__ __forceinline__ unsigned int pk_bf16(float lo, float hi) {
  unsigned int r;
  asm("v_cvt_pk_bf16_f32 %0, %1, %2" : "=v"(r) : "v"(lo), "v"(hi));
  return r;
}
// async global->LDS, 16B per lane; LDS dest = uniform base + lane*16
__device__ __forceinline__ void gll16(const void* g, void* l) {
  __builtin_amdgcn_global_load_lds(
      (const __attribute__((address_space(1))) unsigned int*)g,
      (__attribute__((address_space(3))) unsigned int*)l, 16, 0, 0);
}

// ---------------------------------------------------------------------------
// Kernel 1: copy x1 (cols 0..255) straight to output (cols 0..255)
// ---------------------------------------------------------------------------
__global__ __launch_bounds__(256) void copy_x1_kernel(const float* __restrict__ x,
                                                      float* __restrict__ out) {
  int idx = blockIdx.x * 256 + threadIdx.x;
  int row = idx >> 6;
  int c4  = (idx & 63) * 4;
  *reinterpret_cast<float4*>(&out[(size_t)row * CC + c4]) =
      *reinterpret_cast<const float4*>(&x[(size_t)row * CC + c4]);
}

// ---------------------------------------------------------------------------
// Kernel 2: QKV projection GEMM (MFMA).  C[m][n] = scale * sum_k x[m][k]*W[n][k]
//   x f32 [8192][512] (first 256 cols), W f32 [2048][256].
//   BM=BN=128, BK=32, 256 thr / 4 waves (wr,wc in 2x2), 8 K-iters.
//   Reg-staged f32 -> cvt_pk bf16 -> LDS pad-56 (16B rows, <=4-way).
//   vt_mode=1: scatter-store transposed vt[(b*8+h)*256+e][t].
// ---------------------------------------------------------------------------
#define QSTR 56
__global__ __launch_bounds__(256) void qkv_mfma_kernel(const float* __restrict__ x,
                                                       const float* __restrict__ W,
                                                       unsigned short* __restrict__ out,
                                                       float scale, int vt_mode) {
  __shared__ unsigned short As[128 * QSTR];
  __shared__ unsigned short Bs[128 * QSTR];
  const int tid = threadIdx.x;
  const int lane = tid & 63;
  const int wid = tid >> 6;
  const int wr = wid >> 1, wc = wid & 1;
  const int lo = lane & 31, hi = lane >> 5;
  const int m0 = blockIdx.y * 128;
  const int n0 = blockIdx.x * 128;
  const int srow = tid >> 1;          // staging row 0..127
  const int sc0 = (tid & 1) * 16;     // staging col base

  float4 ra[4], rb[4];
  f32x16 acc[2][2];
#pragma unroll
  for (int a = 0; a < 2; ++a)
#pragma unroll
    for (int b = 0; b < 2; ++b)
#pragma unroll
      for (int r = 0; r < 16; ++r) acc[a][b][r] = 0.f;

  // prologue load k0=0
#pragma unroll
  for (int j = 0; j < 4; ++j) {
    ra[j] = *reinterpret_cast<const float4*>(&x[(size_t)(m0 + srow) * CC + sc0 + 4 * j]);
    rb[j] = *reinterpret_cast<const float4*>(&W[(size_t)(n0 + srow) * EE + sc0 + 4 * j]);
  }

  for (int t = 0; t < 8; ++t) {
    // cvt + ds_write current regs
    {
      union { unsigned int u[4]; short8 v; } u0, u1, w0, w1;
      u0.u[0] = pk_bf16(ra[0].x, ra[0].y); u0.u[1] = pk_bf16(ra[0].z, ra[0].w);
      u0.u[2] = pk_bf16(ra[1].x, ra[1].y); u0.u[3] = pk_bf16(ra[1].z, ra[1].w);
      u1.u[0] = pk_bf16(ra[2].x, ra[2].y); u1.u[1] = pk_bf16(ra[2].z, ra[2].w);
      u1.u[2] = pk_bf16(ra[3].x, ra[3].y); u1.u[3] = pk_bf16(ra[3].z, ra[3].w);
      w0.u[0] = pk_bf16(rb[0].x, rb[0].y); w0.u[1] = pk_bf16(rb[0].z, rb[0].w);
      w0.u[2] = pk_bf16(rb[1].x, rb[1].y); w0.u[3] = pk_bf16(rb[1].z, rb[1].w);
      w1.u[0] = pk_bf16(rb[2].x, rb[2].y); w1.u[1] = pk_bf16(rb[2].z, rb[2].w);
      w1.u[2] = pk_bf16(rb[3].x, rb[3].y); w1.u[3] = pk_bf16(rb[3].z, rb[3].w);
      *reinterpret_cast<short8*>(&As[srow * QSTR + sc0]) = u0.v;
      *reinterpret_cast<short8*>(&As[srow * QSTR + sc0 + 8]) = u1.v;
      *reinterpret_cast<short8*>(&Bs[srow * QSTR + sc0]) = w0.v;
      *reinterpret_cast<short8*>(&Bs[srow * QSTR + sc0 + 8]) = w1.v;
    }
    asm volatile("s_waitcnt lgkmcnt(0)" ::: "memory");
    __builtin_amdgcn_s_barrier();
    __builtin_amdgcn_sched_barrier(0);

    if (t + 1 < 8) {
      int k0 = (t + 1) * 32;
#pragma unroll
      for (int j = 0; j < 4; ++j) {
        ra[j] = *reinterpret_cast<const float4*>(&x[(size_t)(m0 + srow) * CC + k0 + sc0 + 4 * j]);
        rb[j] = *reinterpret_cast<const float4*>(&W[(size_t)(n0 + srow) * EE + k0 + sc0 + 4 * j]);
      }
    }

#pragma unroll
    for (int ks = 0; ks < 2; ++ks) {
      short8 af[2], bf[2];
#pragma unroll
      for (int mi = 0; mi < 2; ++mi)
        af[mi] = *reinterpret_cast<const short8*>(&As[(64 * wr + 32 * mi + lo) * QSTR + ks * 16 + hi * 8]);
#pragma unroll
      for (int ni = 0; ni < 2; ++ni)
        bf[ni] = *reinterpret_cast<const short8*>(&Bs[(64 * wc + 32 * ni + lo) * QSTR + ks * 16 + hi * 8]);
#pragma unroll
      for (int mi = 0; mi < 2; ++mi)
#pragma unroll
        for (int ni = 0; ni < 2; ++ni)
          acc[mi][ni] = __builtin_amdgcn_mfma_f32_32x32x16_bf16(af[mi], bf[ni], acc[mi][ni], 0, 0, 0);
    }
    __builtin_amdgcn_s_barrier();
    __builtin_amdgcn_sched_barrier(0);
  }

  // epilogue
#pragma unroll
  for (int mi = 0; mi < 2; ++mi)
#pragma unroll
    for (int ni = 0; ni < 2; ++ni) {
#pragma unroll
      for (int r = 0; r < 16; ++r) {
        int rr = (r & 3) + 8 * (r >> 2) + 4 * hi;
        int m = m0 + 64 * wr + 32 * mi + rr;
        int n = n0 + 64 * wc + 32 * ni + lo;
        unsigned short val = f2bf(acc[mi][ni][r] * scale);
        if (!vt_mode) {
          out[(size_t)m * HE + n] = val;
        } else {
          out[(((size_t)(m >> 10) * 8 + (n >> 8)) * 256 + (n & 255)) * TT + (m & 1023)] = val;
        }
      }
    }
}

// ---------------------------------------------------------------------------
// Kernel 3: pipelined MFMA attention.
//   512 thr = 8 waves (wq 0..3, ws 0..1); QBLK=128, SBLK=64, 16 K/V tiles.
//   K[64][256] and Vt[256][64] double-buffered, staged by global_load_lds
//   with XOR-granule swizzle (g^=row&7) pre-applied on the global source,
//   un-applied on the ds_read side.  Main loop never drains mid-phase:
//   stage(t+1) -> compute(t) -> vmcnt(0) + raw s_barrier.
// ---------------------------------------------------------------------------
__global__ __launch_bounds__(512, 2) void attn_kernel(const unsigned short* __restrict__ qg,
                                                      const unsigned short* __restrict__ kg,
                                                      const unsigned short* __restrict__ vtg,
                                                      unsigned short* __restrict__ og) {
  __shared__ char smem[133120];
  unsigned short* Kbuf = (unsigned short*)smem;              // 2 x [64][256]
  unsigned short* Vbuf = (unsigned short*)(smem + 65536);    // 2 x [256][64]
  float* lpart = (float*)(smem + 131072);                    // [2][128]
  float* Olds = (float*)smem;                                // epilogue reuse [4][32][256]

  const int tid = threadIdx.x;
  const int lane = tid & 63;
  const int wid = tid >> 6;
  const int wq = wid >> 1, ws = wid & 1;
  const int lo = lane & 31, hi = lane >> 5;

  // XCD-aware bijective swizzle: 8 t-tiles of each (b,h) stay on one XCD
  int logical = (blockIdx.x & 7) * 64 + (blockIdx.x >> 3);
  const int bh = logical >> 3;
  const int t0 = (logical & 7) * 128;
  const int b = bh >> 3, h = bh & 7;
  const size_t qkbase = (size_t)b * TT * HE + (size_t)h * EE;
  const size_t vtbase = (size_t)bh * EE * TT;
  const unsigned short* kg_base = kg + qkbase;
  const unsigned short* vt_base = vtg + vtbase;

  // hoist Q fragments: lane holds q-row (t0+32wq+lo), granules hi, hi+2, ...
  short8 qf[16];
  {
    const unsigned short* qrow = qg + qkbase + (size_t)(t0 + 32 * wq + lo) * HE + hi * 8;
#pragma unroll
    for (int ks = 0; ks < 16; ++ks)
      qf[ks] = *reinterpret_cast<const short8*>(qrow + ks * 16);
  }

  f32x16 Oacc[8];
#pragma unroll
  for (int et = 0; et < 8; ++et)
#pragma unroll
    for (int r = 0; r < 16; ++r) Oacc[et][r] = 0.f;
  float lacc = 0.f;

  // stage helper (macro-free): wave wid stages K rows [8w,8w+8), V rows [32w,32w+32)
  const int k_sub = lane >> 5;        // 0..1
  const int k_g   = lane & 31;
  const int v_sub = lane >> 3;        // 0..7
  const int v_g   = lane & 7;

#define STAGE_TILE(TIDX, BUF)                                                        \
  {                                                                                  \
    const unsigned short* kt = kg_base + (size_t)(TIDX) * 64 * HE;                   \
    const unsigned short* vt = vt_base + (size_t)(TIDX) * 64;                        \
    unsigned short* Kb = Kbuf + (BUF) * (64 * 256);                                  \
    unsigned short* Vb = Vbuf + (BUF) * (256 * 64);                                  \
    _Pragma("unroll")                                                                \
    for (int i = 0; i < 4; ++i) {                                                    \
      int row = 8 * wid + 2 * i + k_sub;                                             \
      int gs = k_g ^ (row & 7);                                                      \
      gll16(kt + (size_t)row * HE + gs * 8, Kb + (8 * wid + 2 * i) * 256);           \
    }                                                                                \
    _Pragma("unroll")                                                                \
    for (int i = 0; i < 4; ++i) {                                                    \
      int row = 32 * wid + 8 * i + v_sub;                                            \
      int gs = v_g ^ (row & 7);                                                      \
      gll16(vt + (size_t)row * TT + gs * 8, Vb + (32 * wid + 8 * i) * 64);           \
    }                                                                                \
  }

  STAGE_TILE(0, 0)
  asm volatile("s_waitcnt vmcnt(0)" ::: "memory");
  __builtin_amdgcn_s_barrier();
  __builtin_amdgcn_sched_barrier(0);

  for (int t = 0; t < 16; ++t) {
    const int cur = t & 1;
    if (t + 1 < 16) STAGE_TILE(t + 1, cur ^ 1)

    const unsigned short* Kb = Kbuf + cur * (64 * 256);
    const unsigned short* Vb = Vbuf + cur * (256 * 64);

    // ---- QK^T (swapped): S^T[32 s x 32 q]
    f32x16 sacc;
#pragma unroll
    for (int r = 0; r < 16; ++r) sacc[r] = 0.f;
    const int srow = 32 * ws + lo;
    const int sxor = srow & 7;
#pragma unroll
    for (int ks = 0; ks < 16; ++ks) {
      int slot = (ks * 2 + hi) ^ sxor;
      short8 kf = *reinterpret_cast<const short8*>(&Kb[srow * 256 + slot * 8]);
      sacc = __builtin_amdgcn_mfma_f32_32x32x16_bf16(kf, qf[ks], sacc, 0, 0, 0);
    }

    // ---- softmax numerator + pack P to PV A-frags (cvt_pk + permlane32_swap)
    short8 pa[2];
#pragma unroll
    for (int ksl = 0; ksl < 2; ++ksl) {
      float p0 = __expf(sacc[8 * ksl + 0]), p1 = __expf(sacc[8 * ksl + 1]);
      float p2 = __expf(sacc[8 * ksl + 2]), p3 = __expf(sacc[8 * ksl + 3]);
      float p4 = __expf(sacc[8 * ksl + 4]), p5 = __expf(sacc[8 * ksl + 5]);
      float p6 = __expf(sacc[8 * ksl + 6]), p7 = __expf(sacc[8 * ksl + 7]);
      lacc += ((p0 + p1) + (p2 + p3)) + ((p4 + p5) + (p6 + p7));
      unsigned int a1 = pk_bf16(p0, p1), a2 = pk_bf16(p2, p3);
      unsigned int b1 = pk_bf16(p4, p5), b2 = pk_bf16(p6, p7);
      uint2v r1 = __builtin_amdgcn_permlane32_swap(a1, b1, false, false);
      uint2v r2 = __builtin_amdgcn_permlane32_swap(a2, b2, false, false);
      union { unsigned int u[4]; short8 v; } uu;
      uu.u[0] = r1[0]; uu.u[1] = r2[0]; uu.u[2] = r1[1]; uu.u[3] = r2[1];
      pa[ksl] = uu.v;
    }

    // ---- PV
    const int exor = lo & 7;
#pragma unroll
    for (int et = 0; et < 8; ++et) {
      const int erow = et * 32 + lo;
#pragma unroll
      for (int ksl = 0; ksl < 2; ++ksl) {
        int slot = (4 * ws + 2 * ksl + hi) ^ exor;
        short8 vf = *reinterpret_cast<const short8*>(&Vb[erow * 64 + slot * 8]);
        Oacc[et] = __builtin_amdgcn_mfma_f32_32x32x16_bf16(pa[ksl], vf, Oacc[et], 0, 0, 0);
      }
    }

    asm volatile("s_waitcnt vmcnt(0)" ::: "memory");
    __builtin_amdgcn_s_barrier();
    __builtin_amdgcn_sched_barrier(0);
  }

  // ---- epilogue: combine ws pairs via LDS (reuse K/V buffers)
  lacc += __shfl_xor(lacc, 32);
  if (hi == 0) lpart[ws * 128 + 32 * wq + lo] = lacc;

  if (ws == 1) {
    float* dst = Olds + wq * (32 * 256);
#pragma unroll
    for (int r = 0; r < 16; ++r) {
      int rr = (r & 3) + 8 * (r >> 2) + 4 * hi;
#pragma unroll
      for (int et = 0; et < 8; ++et)
        dst[rr * 256 + et * 32 + lo] = Oacc[et][r];
    }
  }
  __syncthreads();
  if (ws == 0) {
    const float* src = Olds + wq * (32 * 256);
#pragma unroll
    for (int r = 0; r < 16; ++r) {
      int rr = (r & 3) + 8 * (r >> 2) + 4 * hi;
      float inv = 1.0f / (lpart[32 * wq + rr] + lpart[128 + 32 * wq + rr]);
      int tq = t0 + 32 * wq + rr;
#pragma unroll
      for (int et = 0; et < 8; ++et) {
        float o = (Oacc[et][r] + src[rr * 256 + et * 32 + lo]) * inv;
        og[qkbase + (size_t)tq * HE + et * 32 + lo] = f2bf(o);
      }
    }
  }
#undef STAGE_TILE
}

// ---------------------------------------------------------------------------
// Kernel 4: output projection (MFMA) + bias + residual into out cols 256..511
//   A = ao bf16 [8192][2048], B = Wu f32 [256][2048] -> bf16.
//   BM=64, BN=128, BK=64, 256 thr / 4 waves, 32 K-iters.
// ---------------------------------------------------------------------------
#define PSTR 72
__global__ __launch_bounds__(256) void proj_mfma_kernel(const unsigned short* __restrict__ ao,
                                                        const float* __restrict__ Wu,
                                                        const float* __restrict__ bu,
                                                        const float* __restrict__ x,
                                                        float* __restrict__ out) {
  __shared__ unsigned short As[64 * PSTR];
  __shared__ unsigned short Bs[128 * PSTR];
  const int tid = threadIdx.x;
  const int lane = tid & 63;
  const int wid = tid >> 6;
  const int wr = wid >> 1, wc = wid & 1;
  const int lo = lane & 31, hi = lane >> 5;
  const int m0 = blockIdx.y * 64;
  const int n0 = blockIdx.x * 128;

  const int arow = tid >> 2;            // 0..63
  const int ag0 = (tid & 3) * 2;        // granules {ag0, ag0+1}
  const int brow = tid >> 1;            // 0..127
  const int bg0 = (tid & 1) * 4;        // granules bg0..bg0+4

  short8 raA[2];
  float4 raB[8];
  f32x16 acc[2];
#pragma unroll
  for (int a = 0; a < 2; ++a)
#pragma unroll
    for (int r = 0; r < 16; ++r) acc[a][r] = 0.f;

  // prologue load k0=0
#pragma unroll
  for (int j = 0; j < 2; ++j)
    raA[j] = *reinterpret_cast<const short8*>(&ao[(size_t)(m0 + arow) * HE + (ag0 + j) * 8]);
#pragma unroll
  for (int g = 0; g < 4; ++g) {
    raB[2 * g]     = *reinterpret_cast<const float4*>(&Wu[(size_t)(n0 + brow) * HE + (bg0 + g) * 8]);
    raB[2 * g + 1] = *reinterpret_cast<const float4*>(&Wu[(size_t)(n0 + brow) * HE + (bg0 + g) * 8 + 4]);
  }

  for (int t = 0; t < 32; ++t) {
#pragma unroll
    for (int j = 0; j < 2; ++j)
      *reinterpret_cast<short8*>(&As[arow * PSTR + (ag0 + j) * 8]) = raA[j];
#pragma unroll
    for (int g = 0; g < 4; ++g) {
      union { unsigned int u[4]; short8 v; } w;
      w.u[0] = pk_bf16(raB[2 * g].x, raB[2 * g].y);
      w.u[1] = pk_bf16(raB[2 * g].z, raB[2 * g].w);
      w.u[2] = pk_bf16(raB[2 * g + 1].x, raB[2 * g + 1].y);
      w.u[3] = pk_bf16(raB[2 * g + 1].z, raB[2 * g + 1].w);
      *reinterpret_cast<short8*>(&Bs[brow * PSTR + (bg0 + g) * 8]) = w.v;
    }
    asm volatile("s_waitcnt lgkmcnt(0)" ::: "memory");
    __builtin_amdgcn_s_barrier();
    __builtin_amdgcn_sched_barrier(0);

    if (t + 1 < 32) {
      int k0 = (t + 1) * 64;
#pragma unroll
      for (int j = 0; j < 2; ++j)
        raA[j] = *reinterpret_cast<const short8*>(&ao[(size_t)(m0 + arow) * HE + k0 + (ag0 + j) * 8]);
#pragma unroll
      for (int g = 0; g < 4; ++g) {
        raB[2 * g]     = *reinterpret_cast<const float4*>(&Wu[(size_t)(n0 + brow) * HE + k0 + (bg0 + g) * 8]);
        raB[2 * g + 1] = *reinterpret_cast<const float4*>(&Wu[(size_t)(n0 + brow) * HE + k0 + (bg0 + g) * 8 + 4]);
      }
    }

#pragma unroll
    for (int ks = 0; ks < 4; ++ks) {
      short8 af = *reinterpret_cast<const short8*>(&As[(32 * wr + lo) * PSTR + ks * 16 + hi * 8]);
#pragma unroll
      for (int ni = 0; ni < 2; ++ni) {
        short8 bf = *reinterpret_cast<const short8*>(&Bs[(64 * wc + 32 * ni + lo) * PSTR + ks * 16 + hi * 8]);
        acc[ni] = __builtin_amdgcn_mfma_f32_32x32x16_bf16(af, bf, acc[ni], 0, 0, 0);
      }
    }
    __builtin_amdgcn_s_barrier();
    __builtin_amdgcn_sched_barrier(0);
  }

  // epilogue: += x2 + bias, f32 out
#pragma unroll
  for (int ni = 0; ni < 2; ++ni) {
    int n = n0 + 64 * wc + 32 * ni + lo;
    float bias = bu[n];
#pragma unroll
    for (int r = 0; r < 16; ++r) {
      int rr = (r & 3) + 8 * (r >> 2) + 4 * hi;
      int m = m0 + 32 * wr + rr;
      float o = acc[ni][r] + x[(size_t)m * CC + EE + n] + bias;
      out[(size_t)m * CC + EE + n] = o;
    }
  }
}

// ---------------------------------------------------------------------------
extern "C" void kernel_launch(void* const* d_in, const int* in_sizes, int n_in,
                              void* d_out, int out_size, void* d_ws, size_t ws_size,
                              hipStream_t stream) {
  const float* x  = (const float*)d_in[0];
  const float* Wq = (const float*)d_in[1];
  const float* Wk = (const float*)d_in[2];
  const float* Wv = (const float*)d_in[3];
  const float* Wu = (const float*)d_in[4];
  const float* bu = (const float*)d_in[5];
  float* out = (float*)d_out;

  unsigned short* q  = (unsigned short*)d_ws;
  unsigned short* k  = q + (size_t)MM * HE;
  unsigned short* vt = k + (size_t)MM * HE;
  unsigned short* ao = vt + (size_t)MM * HE;

  const float scale = 0.25f;   // 256^-0.25

  copy_x1_kernel<<<dim3(2048), dim3(256), 0, stream>>>(x, out);

  dim3 gq(HE / 128, MM / 128);   // (16, 64)
  qkv_mfma_kernel<<<gq, dim3(256), 0, stream>>>(x, Wq, q, scale, 0);
  qkv_mfma_kernel<<<gq, dim3(256), 0, stream>>>(x, Wk, k, scale, 0);
  qkv_mfma_kernel<<<gq, dim3(256), 0, stream>>>(x, Wv, vt, 1.0f, 1);

  attn_kernel<<<dim3(512), dim3(512), 0, stream>>>(q, k, vt, ao);

  proj_mfma_kernel<<<dim3(2, 128), dim3(256), 0, stream>>>(ao, Wu, bu, x, out);
}

// Round 4
// 198.141 us; speedup vs baseline: 8.3254x; 1.3141x over previous
//
#include <hip/hip_runtime.h>
#include <hip/hip_bf16.h>

// Problem constants
#define BB 8
#define TT 1024
#define CC 512
#define HH 8
#define EE 256            // head dim (= C/2)
#define MM (BB*TT)        // 8192 rows
#define HE (HH*EE)        // 2048

using short8 = __attribute__((ext_vector_type(8))) short;
using f32x16 = __attribute__((ext_vector_type(16))) float;
using uint2v = __attribute__((ext_vector_type(2))) unsigned int;

__device__ __forceinline__ float bf2f(unsigned short u) {
  union { float f; unsigned int i; } v; v.i = ((unsigned int)u) << 16; return v.f;
}
__device__ __forceinline__ unsigned short f2bf(float f) {
  union { float f; unsigned int i; } v; v.f = f;
  unsigned int r = v.i + 0x7FFFu + ((v.i >> 16) & 1u);  // RNE
  return (unsigned short)(r >> 16);
}
__device__ __forceinline__ unsigned int pk_bf16(float lo, float hi) {
  unsigned int r;
  asm("v_cvt_pk_bf16_f32 %0, %1, %2" : "=v"(r) : "v"(lo), "v"(hi));
  return r;
}
// async global->LDS, 16B per lane; LDS dest = uniform base + lane*16
__device__ __forceinline__ void gll16(const void* g, void* l) {
  __builtin_amdgcn_global_load_lds(
      (const __attribute__((address_space(1))) unsigned int*)g,
      (__attribute__((address_space(3))) unsigned int*)l, 16, 0, 0);
}

// ---------------------------------------------------------------------------
// Kernel 1: copy x1 (cols 0..255) straight to output (cols 0..255)
// ---------------------------------------------------------------------------
__global__ __launch_bounds__(256) void copy_x1_kernel(const float* __restrict__ x,
                                                      float* __restrict__ out) {
  int idx = blockIdx.x * 256 + threadIdx.x;
  int row = idx >> 6;
  int c4  = (idx & 63) * 4;
  *reinterpret_cast<float4*>(&out[(size_t)row * CC + c4]) =
      *reinterpret_cast<const float4*>(&x[(size_t)row * CC + c4]);
}

// ---------------------------------------------------------------------------
// Kernel 2: FUSED QKV projection (MFMA).  For w in {q,k,v}:
//   Cw[m][n] = scale_w * sum_k x[m][k] * Ww[n][k]
//   BM=BN=128, BK=64, 512 thr / 8 waves (2 wr x 4 wc), 4 K-iters, acc[3].
//   A staged once per iter (shared by all 3), saving 2/3 of A traffic.
//   q scale folds log2(e) so attn can use exp2 directly.
//   V epilogue: LDS transpose -> vt[(b*8+h)*256+e][t] with coalesced stores.
//   Grid 1024 1-D, mt-inner XCD swizzle: 8 m-tiles per XCD share B in L2.
// ---------------------------------------------------------------------------
#define FSTR 72
__global__ __launch_bounds__(512) void qkv_fused_kernel(const float* __restrict__ x,
                                                        const float* __restrict__ Wq,
                                                        const float* __restrict__ Wk,
                                                        const float* __restrict__ Wv,
                                                        unsigned short* __restrict__ outq,
                                                        unsigned short* __restrict__ outk,
                                                        unsigned short* __restrict__ outvt) {
  __shared__ unsigned short smem[4 * 128 * FSTR];   // As, Bq, Bk, Bv  (73728 B)
  unsigned short* As = smem;
  unsigned short* Bs[3] = { smem + 128 * FSTR, smem + 2 * 128 * FSTR, smem + 3 * 128 * FSTR };

  const int tid = threadIdx.x;
  const int lane = tid & 63;
  const int wid = tid >> 6;
  const int wr = wid >> 2, wc = wid & 3;
  const int lo = lane & 31, hi = lane >> 5;

  // XCD swizzle: xcd = bid&7 owns m-tiles [xcd*8, xcd*8+8), mt-inner
  int bid = blockIdx.x;
  int r = bid >> 3;
  int mt = (bid & 7) * 8 + (r & 7);
  int nt = r >> 3;                      // 0..15
  const int m0 = mt * 128;
  const int n0 = nt * 128;

  const float* Wp[3] = { Wq, Wk, Wv };
  const float scl[3] = { 0.25f * 1.44269504089f, 0.25f, 1.0f };

  const int srow = tid >> 2;            // 0..127
  const int sc0 = (tid & 3) * 16;       // f32 col base (16 per thread)

  float4 ra[4], rb[3][4];
  f32x16 acc[3][2];
#pragma unroll
  for (int w = 0; w < 3; ++w)
#pragma unroll
    for (int mi = 0; mi < 2; ++mi)
#pragma unroll
      for (int q = 0; q < 16; ++q) acc[w][mi][q] = 0.f;

  // prologue loads (k0 = 0)
#pragma unroll
  for (int j = 0; j < 4; ++j)
    ra[j] = *reinterpret_cast<const float4*>(&x[(size_t)(m0 + srow) * CC + sc0 + 4 * j]);
#pragma unroll
  for (int w = 0; w < 3; ++w)
#pragma unroll
    for (int j = 0; j < 4; ++j)
      rb[w][j] = *reinterpret_cast<const float4*>(&Wp[w][(size_t)(n0 + srow) * EE + sc0 + 4 * j]);

  for (int t = 0; t < 4; ++t) {
    // cvt + ds_write current regs
    {
      union { unsigned int u[4]; short8 v; } p0, p1;
      p0.u[0] = pk_bf16(ra[0].x, ra[0].y); p0.u[1] = pk_bf16(ra[0].z, ra[0].w);
      p0.u[2] = pk_bf16(ra[1].x, ra[1].y); p0.u[3] = pk_bf16(ra[1].z, ra[1].w);
      p1.u[0] = pk_bf16(ra[2].x, ra[2].y); p1.u[1] = pk_bf16(ra[2].z, ra[2].w);
      p1.u[2] = pk_bf16(ra[3].x, ra[3].y); p1.u[3] = pk_bf16(ra[3].z, ra[3].w);
      *reinterpret_cast<short8*>(&As[srow * FSTR + sc0]) = p0.v;
      *reinterpret_cast<short8*>(&As[srow * FSTR + sc0 + 8]) = p1.v;
#pragma unroll
      for (int w = 0; w < 3; ++w) {
        union { unsigned int u[4]; short8 v; } q0, q1;
        q0.u[0] = pk_bf16(rb[w][0].x, rb[w][0].y); q0.u[1] = pk_bf16(rb[w][0].z, rb[w][0].w);
        q0.u[2] = pk_bf16(rb[w][1].x, rb[w][1].y); q0.u[3] = pk_bf16(rb[w][1].z, rb[w][1].w);
        q1.u[0] = pk_bf16(rb[w][2].x, rb[w][2].y); q1.u[1] = pk_bf16(rb[w][2].z, rb[w][2].w);
        q1.u[2] = pk_bf16(rb[w][3].x, rb[w][3].y); q1.u[3] = pk_bf16(rb[w][3].z, rb[w][3].w);
        *reinterpret_cast<short8*>(&Bs[w][srow * FSTR + sc0]) = q0.v;
        *reinterpret_cast<short8*>(&Bs[w][srow * FSTR + sc0 + 8]) = q1.v;
      }
    }
    asm volatile("s_waitcnt lgkmcnt(0)" ::: "memory");
    __builtin_amdgcn_s_barrier();
    __builtin_amdgcn_sched_barrier(0);

    if (t + 1 < 4) {
      int k0 = (t + 1) * 64;
#pragma unroll
      for (int j = 0; j < 4; ++j)
        ra[j] = *reinterpret_cast<const float4*>(&x[(size_t)(m0 + srow) * CC + k0 + sc0 + 4 * j]);
#pragma unroll
      for (int w = 0; w < 3; ++w)
#pragma unroll
        for (int j = 0; j < 4; ++j)
          rb[w][j] = *reinterpret_cast<const float4*>(&Wp[w][(size_t)(n0 + srow) * EE + k0 + sc0 + 4 * j]);
    }

#pragma unroll
    for (int ks = 0; ks < 4; ++ks) {
      short8 af[2];
#pragma unroll
      for (int mi = 0; mi < 2; ++mi)
        af[mi] = *reinterpret_cast<const short8*>(&As[(64 * wr + 32 * mi + lo) * FSTR + ks * 16 + hi * 8]);
#pragma unroll
      for (int w = 0; w < 3; ++w) {
        short8 bf = *reinterpret_cast<const short8*>(&Bs[w][(32 * wc + lo) * FSTR + ks * 16 + hi * 8]);
#pragma unroll
        for (int mi = 0; mi < 2; ++mi)
          acc[w][mi] = __builtin_amdgcn_mfma_f32_32x32x16_bf16(af[mi], bf, acc[w][mi], 0, 0, 0);
      }
    }
    __builtin_amdgcn_s_barrier();
    __builtin_amdgcn_sched_barrier(0);
  }

  // ---- epilogue: q, k direct coalesced stores
#pragma unroll
  for (int w = 0; w < 2; ++w) {
    unsigned short* op = (w == 0) ? outq : outk;
#pragma unroll
    for (int mi = 0; mi < 2; ++mi) {
#pragma unroll
      for (int q = 0; q < 16; ++q) {
        int rr = (q & 3) + 8 * (q >> 2) + 4 * hi;
        int m = m0 + 64 * wr + 32 * mi + rr;
        int n = n0 + 32 * wc + lo;
        op[(size_t)m * HE + n] = f2bf(acc[w][mi][q] * scl[w]);
      }
    }
  }

  // ---- V: LDS transpose then coalesced vt stores
  unsigned short* Tr = smem;            // [128 n][136] m-major rows
  __syncthreads();                      // everyone done with As/Bs
#pragma unroll
  for (int mi = 0; mi < 2; ++mi)
#pragma unroll
    for (int q = 0; q < 16; ++q) {
      int rr = (q & 3) + 8 * (q >> 2) + 4 * hi;
      Tr[(32 * wc + lo) * 136 + 64 * wr + 32 * mi + rr] = f2bf(acc[2][mi][q]);
    }
  __syncthreads();
  {
    const int b = m0 >> 10;
    const int t0m = m0 & 1023;
#pragma unroll
    for (int p = 0; p < 4; ++p) {
      int nr = p * 32 + (tid >> 4);
      int chunk = tid & 15;
      int n = n0 + nr;
      size_t drow = ((size_t)b * 8 + (n >> 8)) * 256 + (n & 255);
      *reinterpret_cast<short8*>(&outvt[drow * TT + t0m + chunk * 8]) =
          *reinterpret_cast<const short8*>(&Tr[nr * 136 + chunk * 8]);
    }
  }
}

// ---------------------------------------------------------------------------
// Kernel 3: pipelined MFMA attention.
//   256 thr = 4 waves, each wave owns 32 q-rows (QBLK=128), SBLK=32,
//   32 K/V tiles, NO s-split (each wave accumulates full O for its rows).
//   K[32][256] + Vt[256][32] double-buffered (64KB+lpart -> 2 blocks/CU).
//   global_load_lds staging with XOR-granule pre-swizzle on global source:
//     K: 16B granule g ^ (row&7);  V: 16B granule g ^ ((row>>1)&3).
//   Main loop: stage(t+1, other buf) -> compute(t) -> vmcnt(0)+barrier.
//   Softmax = exp2 (log2e folded into q scale), P packed in-register via
//   v_cvt_pk_bf16_f32 + permlane32_swap.
// ---------------------------------------------------------------------------
#define SBLK 32
__global__ __launch_bounds__(256, 2) void attn_kernel(const unsigned short* __restrict__ qg,
                                                      const unsigned short* __restrict__ kg,
                                                      const unsigned short* __restrict__ vtg,
                                                      unsigned short* __restrict__ og) {
  __shared__ char smem[66048];
  unsigned short* Kbuf = (unsigned short*)smem;              // 2 x [32][256]
  unsigned short* Vbuf = (unsigned short*)(smem + 32768);    // 2 x [256][32]
  float* lpart = (float*)(smem + 65536);                     // [128]

  const int tid = threadIdx.x;
  const int lane = tid & 63;
  const int wid = tid >> 6;           // 0..3: q-subtile
  const int lo = lane & 31, hi = lane >> 5;

  // XCD-aware bijective swizzle: 8 t-tiles of each (b,h) stay on one XCD
  int logical = (blockIdx.x & 7) * 64 + (blockIdx.x >> 3);
  const int bh = logical >> 3;
  const int t0 = (logical & 7) * 128;
  const int b = bh >> 3, h = bh & 7;
  const size_t qkbase = (size_t)b * TT * HE + (size_t)h * EE;
  const size_t vtbase = (size_t)bh * EE * TT;
  const unsigned short* kg_base = kg + qkbase;
  const unsigned short* vt_base = vtg + vtbase;

  // hoist Q fragments (B-operand): lane holds q-row t0+32*wid+lo
  short8 qf[16];
  {
    const unsigned short* qrow = qg + qkbase + (size_t)(t0 + 32 * wid + lo) * HE + hi * 8;
#pragma unroll
    for (int ks = 0; ks < 16; ++ks)
      qf[ks] = *reinterpret_cast<const short8*>(qrow + ks * 16);
  }

  f32x16 Oacc[8];
#pragma unroll
  for (int et = 0; et < 8; ++et)
#pragma unroll
    for (int q = 0; q < 16; ++q) Oacc[et][q] = 0.f;
  float lacc = 0.f;

  // staging lane decomposition
  const int k_sub = lane >> 5;        // K: 2 rows / instr
  const int k_g   = lane & 31;
  const int v_er  = lane >> 2;        // V: 16 rows / instr
  const int v_g   = lane & 3;
  const int v_gs  = v_g ^ ((lane >> 3) & 3);

#define STAGE_TILE(TIDX, BUF)                                                        \
  {                                                                                  \
    const unsigned short* kt = kg_base + (size_t)(TIDX) * SBLK * HE;                 \
    const unsigned short* vt = vt_base + (size_t)(TIDX) * SBLK;                      \
    unsigned short* Kb = Kbuf + (BUF) * (SBLK * 256);                                \
    unsigned short* Vb = Vbuf + (BUF) * (256 * SBLK);                                \
    _Pragma("unroll")                                                                \
    for (int i = 0; i < 4; ++i) {                                                    \
      int row = 8 * wid + 2 * i + k_sub;                                             \
      int gs = k_g ^ (row & 7);                                                      \
      gll16(kt + (size_t)row * HE + gs * 8, Kb + (8 * wid + 2 * i) * 256);           \
    }                                                                                \
    _Pragma("unroll")                                                                \
    for (int i = 0; i < 4; ++i) {                                                    \
      int row = 64 * wid + 16 * i + v_er;                                            \
      gll16(vt + (size_t)row * TT + v_gs * 8, Vb + (64 * wid + 16 * i) * SBLK);      \
    }                                                                                \
  }

  STAGE_TILE(0, 0)
  asm volatile("s_waitcnt vmcnt(0)" ::: "memory");
  __builtin_amdgcn_s_barrier();
  __builtin_amdgcn_sched_barrier(0);

  for (int t = 0; t < 32; ++t) {
    const int cur = t & 1;
    if (t + 1 < 32) STAGE_TILE(t + 1, cur ^ 1)

    const unsigned short* Kb = Kbuf + cur * (SBLK * 256);
    const unsigned short* Vb = Vbuf + cur * (256 * SBLK);

    // ---- QK^T (swapped): S^T[32 s x 32 q]
    f32x16 sacc;
#pragma unroll
    for (int q = 0; q < 16; ++q) sacc[q] = 0.f;
    const int sxor = lo & 7;
#pragma unroll
    for (int ks = 0; ks < 16; ++ks) {
      int slot = (ks * 2 + hi) ^ sxor;
      short8 kf = *reinterpret_cast<const short8*>(&Kb[lo * 256 + slot * 8]);
      sacc = __builtin_amdgcn_mfma_f32_32x32x16_bf16(kf, qf[ks], sacc, 0, 0, 0);
    }

    // ---- softmax numerator (exp2; log2e pre-folded) + pack to A-frags
    short8 pa[2];
#pragma unroll
    for (int ksl = 0; ksl < 2; ++ksl) {
      float p0 = __builtin_amdgcn_exp2f(sacc[8 * ksl + 0]);
      float p1 = __builtin_amdgcn_exp2f(sacc[8 * ksl + 1]);
      float p2 = __builtin_amdgcn_exp2f(sacc[8 * ksl + 2]);
      float p3 = __builtin_amdgcn_exp2f(sacc[8 * ksl + 3]);
      float p4 = __builtin_amdgcn_exp2f(sacc[8 * ksl + 4]);
      float p5 = __builtin_amdgcn_exp2f(sacc[8 * ksl + 5]);
      float p6 = __builtin_amdgcn_exp2f(sacc[8 * ksl + 6]);
      float p7 = __builtin_amdgcn_exp2f(sacc[8 * ksl + 7]);
      lacc += ((p0 + p1) + (p2 + p3)) + ((p4 + p5) + (p6 + p7));
      unsigned int a1 = pk_bf16(p0, p1), a2 = pk_bf16(p2, p3);
      unsigned int b1 = pk_bf16(p4, p5), b2 = pk_bf16(p6, p7);
      uint2v r1 = __builtin_amdgcn_permlane32_swap(a1, b1, false, false);
      uint2v r2 = __builtin_amdgcn_permlane32_swap(a2, b2, false, false);
      union { unsigned int u[4]; short8 v; } uu;
      uu.u[0] = r1[0]; uu.u[1] = r2[0]; uu.u[2] = r1[1]; uu.u[3] = r2[1];
      pa[ksl] = uu.v;
    }

    // ---- PV: O[32q][256e] += P[32q][32s] * V[32s][256e]
    const int vxor = (lo >> 1) & 3;
#pragma unroll
    for (int et = 0; et < 8; ++et) {
      const int erow = et * 32 + lo;
#pragma unroll
      for (int ksl = 0; ksl < 2; ++ksl) {
        int slot = (2 * ksl + hi) ^ vxor;
        short8 vf = *reinterpret_cast<const short8*>(&Vb[erow * SBLK + slot * 8]);
        Oacc[et] = __builtin_amdgcn_mfma_f32_32x32x16_bf16(pa[ksl], vf, Oacc[et], 0, 0, 0);
      }
    }

    asm volatile("s_waitcnt vmcnt(0)" ::: "memory");
    __builtin_amdgcn_s_barrier();
    __builtin_amdgcn_sched_barrier(0);
  }

  // ---- epilogue: fold hi halves of lacc, redistribute by q-row, store
  lacc += __shfl_xor(lacc, 32);
  if (hi == 0) lpart[wid * 32 + lo] = lacc;
  __syncthreads();
#pragma unroll
  for (int q = 0; q < 16; ++q) {
    int rr = (q & 3) + 8 * (q >> 2) + 4 * hi;
    float inv = 1.0f / lpart[wid * 32 + rr];
    int tq = t0 + 32 * wid + rr;
#pragma unroll
    for (int et = 0; et < 8; ++et)
      og[qkbase + (size_t)tq * HE + et * 32 + lo] = f2bf(Oacc[et][q] * inv);
  }
#undef STAGE_TILE
}

// ---------------------------------------------------------------------------
// Kernel 4: output projection (MFMA) + bias + residual into out cols 256..511
//   A = ao bf16 [8192][2048], B = Wu f32 [256][2048].
//   BM=64, BN=128, BK=64, 256 thr / 4 waves, 32 K-iters.
// ---------------------------------------------------------------------------
#define PSTR 72
__global__ __launch_bounds__(256) void proj_mfma_kernel(const unsigned short* __restrict__ ao,
                                                        const float* __restrict__ Wu,
                                                        const float* __restrict__ bu,
                                                        const float* __restrict__ x,
                                                        float* __restrict__ out) {
  __shared__ unsigned short As[64 * PSTR];
  __shared__ unsigned short Bs[128 * PSTR];
  const int tid = threadIdx.x;
  const int lane = tid & 63;
  const int wid = tid >> 6;
  const int wr = wid >> 1, wc = wid & 1;
  const int lo = lane & 31, hi = lane >> 5;
  const int m0 = blockIdx.y * 64;
  const int n0 = blockIdx.x * 128;

  const int arow = tid >> 2;            // 0..63
  const int ag0 = (tid & 3) * 2;        // granules {ag0, ag0+1}
  const int brow = tid >> 1;            // 0..127
  const int bg0 = (tid & 1) * 4;        // granules bg0..bg0+4

  short8 raA[2];
  float4 raB[8];
  f32x16 acc[2];
#pragma unroll
  for (int a = 0; a < 2; ++a)
#pragma unroll
    for (int q = 0; q < 16; ++q) acc[a][q] = 0.f;

  // prologue load k0=0
#pragma unroll
  for (int j = 0; j < 2; ++j)
    raA[j] = *reinterpret_cast<const short8*>(&ao[(size_t)(m0 + arow) * HE + (ag0 + j) * 8]);
#pragma unroll
  for (int g = 0; g < 4; ++g) {
    raB[2 * g]     = *reinterpret_cast<const float4*>(&Wu[(size_t)(n0 + brow) * HE + (bg0 + g) * 8]);
    raB[2 * g + 1] = *reinterpret_cast<const float4*>(&Wu[(size_t)(n0 + brow) * HE + (bg0 + g) * 8 + 4]);
  }

  for (int t = 0; t < 32; ++t) {
#pragma unroll
    for (int j = 0; j < 2; ++j)
      *reinterpret_cast<short8*>(&As[arow * PSTR + (ag0 + j) * 8]) = raA[j];
#pragma unroll
    for (int g = 0; g < 4; ++g) {
      union { unsigned int u[4]; short8 v; } w;
      w.u[0] = pk_bf16(raB[2 * g].x, raB[2 * g].y);
      w.u[1] = pk_bf16(raB[2 * g].z, raB[2 * g].w);
      w.u[2] = pk_bf16(raB[2 * g + 1].x, raB[2 * g + 1].y);
      w.u[3] = pk_bf16(raB[2 * g + 1].z, raB[2 * g + 1].w);
      *reinterpret_cast<short8*>(&Bs[brow * PSTR + (bg0 + g) * 8]) = w.v;
    }
    asm volatile("s_waitcnt lgkmcnt(0)" ::: "memory");
    __builtin_amdgcn_s_barrier();
    __builtin_amdgcn_sched_barrier(0);

    if (t + 1 < 32) {
      int k0 = (t + 1) * 64;
#pragma unroll
      for (int j = 0; j < 2; ++j)
        raA[j] = *reinterpret_cast<const short8*>(&ao[(size_t)(m0 + arow) * HE + k0 + (ag0 + j) * 8]);
#pragma unroll
      for (int g = 0; g < 4; ++g) {
        raB[2 * g]     = *reinterpret_cast<const float4*>(&Wu[(size_t)(n0 + brow) * HE + k0 + (bg0 + g) * 8]);
        raB[2 * g + 1] = *reinterpret_cast<const float4*>(&Wu[(size_t)(n0 + brow) * HE + k0 + (bg0 + g) * 8 + 4]);
      }
    }

#pragma unroll
    for (int ks = 0; ks < 4; ++ks) {
      short8 af = *reinterpret_cast<const short8*>(&As[(32 * wr + lo) * PSTR + ks * 16 + hi * 8]);
#pragma unroll
      for (int ni = 0; ni < 2; ++ni) {
        short8 bf = *reinterpret_cast<const short8*>(&Bs[(64 * wc + 32 * ni + lo) * PSTR + ks * 16 + hi * 8]);
        acc[ni] = __builtin_amdgcn_mfma_f32_32x32x16_bf16(af, bf, acc[ni], 0, 0, 0);
      }
    }
    __builtin_amdgcn_s_barrier();
    __builtin_amdgcn_sched_barrier(0);
  }

  // epilogue: += x2 + bias, f32 out
#pragma unroll
  for (int ni = 0; ni < 2; ++ni) {
    int n = n0 + 64 * wc + 32 * ni + lo;
    float bias = bu[n];
#pragma unroll
    for (int q = 0; q < 16; ++q) {
      int rr = (q & 3) + 8 * (q >> 2) + 4 * hi;
      int m = m0 + 32 * wr + rr;
      float o = acc[ni][q] + x[(size_t)m * CC + EE + n] + bias;
      out[(size_t)m * CC + EE + n] = o;
    }
  }
}

// ---------------------------------------------------------------------------
extern "C" void kernel_launch(void* const* d_in, const int* in_sizes, int n_in,
                              void* d_out, int out_size, void* d_ws, size_t ws_size,
                              hipStream_t stream) {
  const float* x  = (const float*)d_in[0];
  const float* Wq = (const float*)d_in[1];
  const float* Wk = (const float*)d_in[2];
  const float* Wv = (const float*)d_in[3];
  const float* Wu = (const float*)d_in[4];
  const float* bu = (const float*)d_in[5];
  float* out = (float*)d_out;

  unsigned short* q  = (unsigned short*)d_ws;
  unsigned short* k  = q + (size_t)MM * HE;
  unsigned short* vt = k + (size_t)MM * HE;
  unsigned short* ao = vt + (size_t)MM * HE;

  copy_x1_kernel<<<dim3(2048), dim3(256), 0, stream>>>(x, out);

  qkv_fused_kernel<<<dim3(1024), dim3(512), 0, stream>>>(x, Wq, Wk, Wv, q, k, vt);

  attn_kernel<<<dim3(512), dim3(256), 0, stream>>>(q, k, vt, ao);

  proj_mfma_kernel<<<dim3(2, 128), dim3(256), 0, stream>>>(ao, Wu, bu, x, out);
}

// Round 5
// 187.227 us; speedup vs baseline: 8.8107x; 1.0583x over previous
//
#include <hip/hip_runtime.h>
#include <hip/hip_bf16.h>

// Problem constants
#define BB 8
#define TT 1024
#define CC 512
#define HH 8
#define EE 256            // head dim (= C/2)
#define MM (BB*TT)        // 8192 rows
#define HE (HH*EE)        // 2048

using short8 = __attribute__((ext_vector_type(8))) short;
using f32x16 = __attribute__((ext_vector_type(16))) float;
using uint2v = __attribute__((ext_vector_type(2))) unsigned int;

__device__ __forceinline__ float bf2f(unsigned short u) {
  union { float f; unsigned int i; } v; v.i = ((unsigned int)u) << 16; return v.f;
}
__device__ __forceinline__ unsigned short f2bf(float f) {
  union { float f; unsigned int i; } v; v.f = f;
  unsigned int r = v.i + 0x7FFFu + ((v.i >> 16) & 1u);  // RNE
  return (unsigned short)(r >> 16);
}
__device__ __forceinline__ unsigned int pk_bf16(float lo, float hi) {
  unsigned int r;
  asm("v_cvt_pk_bf16_f32 %0, %1, %2" : "=v"(r) : "v"(lo), "v"(hi));
  return r;
}
// async global->LDS, 16B per lane; LDS dest = uniform base + lane*16
__device__ __forceinline__ void gll16(const void* g, void* l) {
  __builtin_amdgcn_global_load_lds(
      (const __attribute__((address_space(1))) unsigned int*)g,
      (__attribute__((address_space(3))) unsigned int*)l, 16, 0, 0);
}

// ---------------------------------------------------------------------------
// Kernel 1: FUSED QKV projection (MFMA) + x1 passthrough copy.
//   For w in {q,k,v}:  Cw[m][n] = scale_w * sum_k x[m][k] * Ww[n][k]
//   BM=BN=128, BK=64, 512 thr / 8 waves (2 wr x 4 wc), 4 K-iters, acc[3].
//   A staged once per iter (shared by all 3).  nt==0 blocks also store the
//   x1 tile (f32 regs they already loaded) to out cols 0..255 (copy fusion).
//   q scale folds log2(e) so attn can use exp2 directly.
//   V epilogue: LDS transpose -> vt[(b*8+h)*256+e][t] coalesced stores.
//   Grid 1024 1-D, mt-inner XCD swizzle: 8 m-tiles per XCD share B in L2.
// ---------------------------------------------------------------------------
#define FSTR 72
__global__ __launch_bounds__(512) void qkv_fused_kernel(const float* __restrict__ x,
                                                        const float* __restrict__ Wq,
                                                        const float* __restrict__ Wk,
                                                        const float* __restrict__ Wv,
                                                        unsigned short* __restrict__ outq,
                                                        unsigned short* __restrict__ outk,
                                                        unsigned short* __restrict__ outvt,
                                                        float* __restrict__ out) {
  __shared__ unsigned short smem[4 * 128 * FSTR];   // As, Bq, Bk, Bv  (73728 B)
  unsigned short* As = smem;
  unsigned short* Bs[3] = { smem + 128 * FSTR, smem + 2 * 128 * FSTR, smem + 3 * 128 * FSTR };

  const int tid = threadIdx.x;
  const int lane = tid & 63;
  const int wid = tid >> 6;
  const int wr = wid >> 2, wc = wid & 3;
  const int lo = lane & 31, hi = lane >> 5;

  // XCD swizzle: xcd = bid&7 owns m-tiles [xcd*8, xcd*8+8), mt-inner
  int bid = blockIdx.x;
  int r = bid >> 3;
  int mt = (bid & 7) * 8 + (r & 7);
  int nt = r >> 3;                      // 0..15
  const int m0 = mt * 128;
  const int n0 = nt * 128;

  const float* Wp[3] = { Wq, Wk, Wv };
  const float scl[3] = { 0.25f * 1.44269504089f, 0.25f, 1.0f };

  const int srow = tid >> 2;            // 0..127
  const int sc0 = (tid & 3) * 16;       // f32 col base (16 per thread)

  float4 ra[4], rb[3][4];
  f32x16 acc[3][2];
#pragma unroll
  for (int w = 0; w < 3; ++w)
#pragma unroll
    for (int mi = 0; mi < 2; ++mi)
#pragma unroll
      for (int q = 0; q < 16; ++q) acc[w][mi][q] = 0.f;

  // prologue loads (k0 = 0)
#pragma unroll
  for (int j = 0; j < 4; ++j)
    ra[j] = *reinterpret_cast<const float4*>(&x[(size_t)(m0 + srow) * CC + sc0 + 4 * j]);
#pragma unroll
  for (int w = 0; w < 3; ++w)
#pragma unroll
    for (int j = 0; j < 4; ++j)
      rb[w][j] = *reinterpret_cast<const float4*>(&Wp[w][(size_t)(n0 + srow) * EE + sc0 + 4 * j]);

  for (int t = 0; t < 4; ++t) {
    // cvt + ds_write current regs
    {
      union { unsigned int u[4]; short8 v; } p0, p1;
      p0.u[0] = pk_bf16(ra[0].x, ra[0].y); p0.u[1] = pk_bf16(ra[0].z, ra[0].w);
      p0.u[2] = pk_bf16(ra[1].x, ra[1].y); p0.u[3] = pk_bf16(ra[1].z, ra[1].w);
      p1.u[0] = pk_bf16(ra[2].x, ra[2].y); p1.u[1] = pk_bf16(ra[2].z, ra[2].w);
      p1.u[2] = pk_bf16(ra[3].x, ra[3].y); p1.u[3] = pk_bf16(ra[3].z, ra[3].w);
      *reinterpret_cast<short8*>(&As[srow * FSTR + sc0]) = p0.v;
      *reinterpret_cast<short8*>(&As[srow * FSTR + sc0 + 8]) = p1.v;
#pragma unroll
      for (int w = 0; w < 3; ++w) {
        union { unsigned int u[4]; short8 v; } q0, q1;
        q0.u[0] = pk_bf16(rb[w][0].x, rb[w][0].y); q0.u[1] = pk_bf16(rb[w][0].z, rb[w][0].w);
        q0.u[2] = pk_bf16(rb[w][1].x, rb[w][1].y); q0.u[3] = pk_bf16(rb[w][1].z, rb[w][1].w);
        q1.u[0] = pk_bf16(rb[w][2].x, rb[w][2].y); q1.u[1] = pk_bf16(rb[w][2].z, rb[w][2].w);
        q1.u[2] = pk_bf16(rb[w][3].x, rb[w][3].y); q1.u[3] = pk_bf16(rb[w][3].z, rb[w][3].w);
        *reinterpret_cast<short8*>(&Bs[w][srow * FSTR + sc0]) = q0.v;
        *reinterpret_cast<short8*>(&Bs[w][srow * FSTR + sc0 + 8]) = q1.v;
      }
    }
    // fused x1 copy: nt==0 blocks store the x-tile slice (still in ra)
    if (n0 == 0) {
      int k0 = t * 64;
#pragma unroll
      for (int j = 0; j < 4; ++j)
        *reinterpret_cast<float4*>(&out[(size_t)(m0 + srow) * CC + k0 + sc0 + 4 * j]) = ra[j];
    }
    asm volatile("s_waitcnt lgkmcnt(0)" ::: "memory");
    __builtin_amdgcn_s_barrier();
    __builtin_amdgcn_sched_barrier(0);

    if (t + 1 < 4) {
      int k0 = (t + 1) * 64;
#pragma unroll
      for (int j = 0; j < 4; ++j)
        ra[j] = *reinterpret_cast<const float4*>(&x[(size_t)(m0 + srow) * CC + k0 + sc0 + 4 * j]);
#pragma unroll
      for (int w = 0; w < 3; ++w)
#pragma unroll
        for (int j = 0; j < 4; ++j)
          rb[w][j] = *reinterpret_cast<const float4*>(&Wp[w][(size_t)(n0 + srow) * EE + k0 + sc0 + 4 * j]);
    }

    __builtin_amdgcn_s_setprio(1);
#pragma unroll
    for (int ks = 0; ks < 4; ++ks) {
      short8 af[2];
#pragma unroll
      for (int mi = 0; mi < 2; ++mi)
        af[mi] = *reinterpret_cast<const short8*>(&As[(64 * wr + 32 * mi + lo) * FSTR + ks * 16 + hi * 8]);
#pragma unroll
      for (int w = 0; w < 3; ++w) {
        short8 bf = *reinterpret_cast<const short8*>(&Bs[w][(32 * wc + lo) * FSTR + ks * 16 + hi * 8]);
#pragma unroll
        for (int mi = 0; mi < 2; ++mi)
          acc[w][mi] = __builtin_amdgcn_mfma_f32_32x32x16_bf16(af[mi], bf, acc[w][mi], 0, 0, 0);
      }
    }
    __builtin_amdgcn_s_setprio(0);
    __builtin_amdgcn_s_barrier();
    __builtin_amdgcn_sched_barrier(0);
  }

  // ---- epilogue: q, k direct coalesced stores
#pragma unroll
  for (int w = 0; w < 2; ++w) {
    unsigned short* op = (w == 0) ? outq : outk;
#pragma unroll
    for (int mi = 0; mi < 2; ++mi) {
#pragma unroll
      for (int q = 0; q < 16; ++q) {
        int rr = (q & 3) + 8 * (q >> 2) + 4 * hi;
        int m = m0 + 64 * wr + 32 * mi + rr;
        int n = n0 + 32 * wc + lo;
        op[(size_t)m * HE + n] = f2bf(acc[w][mi][q] * scl[w]);
      }
    }
  }

  // ---- V: LDS transpose then coalesced vt stores
  unsigned short* Tr = smem;            // [128 n][136] m-major rows
  __syncthreads();                      // everyone done with As/Bs
#pragma unroll
  for (int mi = 0; mi < 2; ++mi)
#pragma unroll
    for (int q = 0; q < 16; ++q) {
      int rr = (q & 3) + 8 * (q >> 2) + 4 * hi;
      Tr[(32 * wc + lo) * 136 + 64 * wr + 32 * mi + rr] = f2bf(acc[2][mi][q]);
    }
  __syncthreads();
  {
    const int b = m0 >> 10;
    const int t0m = m0 & 1023;
#pragma unroll
    for (int p = 0; p < 4; ++p) {
      int nr = p * 32 + (tid >> 4);
      int chunk = tid & 15;
      int n = n0 + nr;
      size_t drow = ((size_t)b * 8 + (n >> 8)) * 256 + (n & 255);
      *reinterpret_cast<short8*>(&outvt[drow * TT + t0m + chunk * 8]) =
          *reinterpret_cast<const short8*>(&Tr[nr * 136 + chunk * 8]);
    }
  }
}

// ---------------------------------------------------------------------------
// Kernel 2: pipelined MFMA attention.
//   256 thr = 4 waves, each wave owns 32 q-rows (QBLK=128), SBLK=32,
//   32 K/V tiles, no s-split.  K[32][256] + Vt[256][32] double-buffered.
//   global_load_lds staging with XOR-granule pre-swizzle on global source.
//   Main loop: stage(t+1, other buf) -> compute(t) -> vmcnt(0)+barrier.
//   Softmax = exp2 (log2e folded into q scale), P packed in-register via
//   v_cvt_pk_bf16_f32 + permlane32_swap.  setprio around MFMA clusters.
// ---------------------------------------------------------------------------
#define SBLK 32
__global__ __launch_bounds__(256, 2) void attn_kernel(const unsigned short* __restrict__ qg,
                                                      const unsigned short* __restrict__ kg,
                                                      const unsigned short* __restrict__ vtg,
                                                      unsigned short* __restrict__ og) {
  __shared__ char smem[66048];
  unsigned short* Kbuf = (unsigned short*)smem;              // 2 x [32][256]
  unsigned short* Vbuf = (unsigned short*)(smem + 32768);    // 2 x [256][32]
  float* lpart = (float*)(smem + 65536);                     // [128]

  const int tid = threadIdx.x;
  const int lane = tid & 63;
  const int wid = tid >> 6;           // 0..3: q-subtile
  const int lo = lane & 31, hi = lane >> 5;

  // XCD-aware bijective swizzle: 8 t-tiles of each (b,h) stay on one XCD
  int logical = (blockIdx.x & 7) * 64 + (blockIdx.x >> 3);
  const int bh = logical >> 3;
  const int t0 = (logical & 7) * 128;
  const int b = bh >> 3, h = bh & 7;
  const size_t qkbase = (size_t)b * TT * HE + (size_t)h * EE;
  const size_t vtbase = (size_t)bh * EE * TT;
  const unsigned short* kg_base = kg + qkbase;
  const unsigned short* vt_base = vtg + vtbase;

  // hoist Q fragments (B-operand): lane holds q-row t0+32*wid+lo
  short8 qf[16];
  {
    const unsigned short* qrow = qg + qkbase + (size_t)(t0 + 32 * wid + lo) * HE + hi * 8;
#pragma unroll
    for (int ks = 0; ks < 16; ++ks)
      qf[ks] = *reinterpret_cast<const short8*>(qrow + ks * 16);
  }

  f32x16 Oacc[8];
#pragma unroll
  for (int et = 0; et < 8; ++et)
#pragma unroll
    for (int q = 0; q < 16; ++q) Oacc[et][q] = 0.f;
  float lacc = 0.f;

  // staging lane decomposition
  const int k_sub = lane >> 5;        // K: 2 rows / instr
  const int k_g   = lane & 31;
  const int v_er  = lane >> 2;        // V: 16 rows / instr
  const int v_g   = lane & 3;
  const int v_gs  = v_g ^ ((lane >> 3) & 3);

#define STAGE_TILE(TIDX, BUF)                                                        \
  {                                                                                  \
    const unsigned short* kt = kg_base + (size_t)(TIDX) * SBLK * HE;                 \
    const unsigned short* vt = vt_base + (size_t)(TIDX) * SBLK;                      \
    unsigned short* Kb = Kbuf + (BUF) * (SBLK * 256);                                \
    unsigned short* Vb = Vbuf + (BUF) * (256 * SBLK);                                \
    _Pragma("unroll")                                                                \
    for (int i = 0; i < 4; ++i) {                                                    \
      int row = 8 * wid + 2 * i + k_sub;                                             \
      int gs = k_g ^ (row & 7);                                                      \
      gll16(kt + (size_t)row * HE + gs * 8, Kb + (8 * wid + 2 * i) * 256);           \
    }                                                                                \
    _Pragma("unroll")                                                                \
    for (int i = 0; i < 4; ++i) {                                                    \
      int row = 64 * wid + 16 * i + v_er;                                            \
      gll16(vt + (size_t)row * TT + v_gs * 8, Vb + (64 * wid + 16 * i) * SBLK);      \
    }                                                                                \
  }

  STAGE_TILE(0, 0)
  asm volatile("s_waitcnt vmcnt(0)" ::: "memory");
  __builtin_amdgcn_s_barrier();
  __builtin_amdgcn_sched_barrier(0);

  for (int t = 0; t < 32; ++t) {
    const int cur = t & 1;
    if (t + 1 < 32) STAGE_TILE(t + 1, cur ^ 1)

    const unsigned short* Kb = Kbuf + cur * (SBLK * 256);
    const unsigned short* Vb = Vbuf + cur * (256 * SBLK);

    // ---- QK^T (swapped): S^T[32 s x 32 q]
    f32x16 sacc;
#pragma unroll
    for (int q = 0; q < 16; ++q) sacc[q] = 0.f;
    const int sxor = lo & 7;
    __builtin_amdgcn_s_setprio(1);
#pragma unroll
    for (int ks = 0; ks < 16; ++ks) {
      int slot = (ks * 2 + hi) ^ sxor;
      short8 kf = *reinterpret_cast<const short8*>(&Kb[lo * 256 + slot * 8]);
      sacc = __builtin_amdgcn_mfma_f32_32x32x16_bf16(kf, qf[ks], sacc, 0, 0, 0);
    }
    __builtin_amdgcn_s_setprio(0);

    // ---- softmax numerator (exp2; log2e pre-folded) + pack to A-frags
    short8 pa[2];
#pragma unroll
    for (int ksl = 0; ksl < 2; ++ksl) {
      float p0 = __builtin_amdgcn_exp2f(sacc[8 * ksl + 0]);
      float p1 = __builtin_amdgcn_exp2f(sacc[8 * ksl + 1]);
      float p2 = __builtin_amdgcn_exp2f(sacc[8 * ksl + 2]);
      float p3 = __builtin_amdgcn_exp2f(sacc[8 * ksl + 3]);
      float p4 = __builtin_amdgcn_exp2f(sacc[8 * ksl + 4]);
      float p5 = __builtin_amdgcn_exp2f(sacc[8 * ksl + 5]);
      float p6 = __builtin_amdgcn_exp2f(sacc[8 * ksl + 6]);
      float p7 = __builtin_amdgcn_exp2f(sacc[8 * ksl + 7]);
      lacc += ((p0 + p1) + (p2 + p3)) + ((p4 + p5) + (p6 + p7));
      unsigned int a1 = pk_bf16(p0, p1), a2 = pk_bf16(p2, p3);
      unsigned int b1 = pk_bf16(p4, p5), b2 = pk_bf16(p6, p7);
      uint2v r1 = __builtin_amdgcn_permlane32_swap(a1, b1, false, false);
      uint2v r2 = __builtin_amdgcn_permlane32_swap(a2, b2, false, false);
      union { unsigned int u[4]; short8 v; } uu;
      uu.u[0] = r1[0]; uu.u[1] = r2[0]; uu.u[2] = r1[1]; uu.u[3] = r2[1];
      pa[ksl] = uu.v;
    }

    // ---- PV: O[32q][256e] += P[32q][32s] * V[32s][256e]
    const int vxor = (lo >> 1) & 3;
    __builtin_amdgcn_s_setprio(1);
#pragma unroll
    for (int et = 0; et < 8; ++et) {
      const int erow = et * 32 + lo;
#pragma unroll
      for (int ksl = 0; ksl < 2; ++ksl) {
        int slot = (2 * ksl + hi) ^ vxor;
        short8 vf = *reinterpret_cast<const short8*>(&Vb[erow * SBLK + slot * 8]);
        Oacc[et] = __builtin_amdgcn_mfma_f32_32x32x16_bf16(pa[ksl], vf, Oacc[et], 0, 0, 0);
      }
    }
    __builtin_amdgcn_s_setprio(0);

    asm volatile("s_waitcnt vmcnt(0)" ::: "memory");
    __builtin_amdgcn_s_barrier();
    __builtin_amdgcn_sched_barrier(0);
  }

  // ---- epilogue: fold hi halves of lacc, redistribute by q-row, store
  lacc += __shfl_xor(lacc, 32);
  if (hi == 0) lpart[wid * 32 + lo] = lacc;
  __syncthreads();
#pragma unroll
  for (int q = 0; q < 16; ++q) {
    int rr = (q & 3) + 8 * (q >> 2) + 4 * hi;
    float inv = 1.0f / lpart[wid * 32 + rr];
    int tq = t0 + 32 * wid + rr;
#pragma unroll
    for (int et = 0; et < 8; ++et)
      og[qkbase + (size_t)tq * HE + et * 32 + lo] = f2bf(Oacc[et][q] * inv);
  }
#undef STAGE_TILE
}

// ---------------------------------------------------------------------------
// Kernel 3: output projection (MFMA) + bias + residual into out cols 256..511
//   A = ao bf16 [8192][2048], B = Wu f32 [256][2048].
//   BM=64, BN=128, BK=64, 256 thr / 4 waves, 32 K-iters.
//   1-D grid 256 with XCD swizzle: each XCD keeps the whole 2MB Wu in L2.
// ---------------------------------------------------------------------------
#define PSTR 72
__global__ __launch_bounds__(256) void proj_mfma_kernel(const unsigned short* __restrict__ ao,
                                                        const float* __restrict__ Wu,
                                                        const float* __restrict__ bu,
                                                        const float* __restrict__ x,
                                                        float* __restrict__ out) {
  __shared__ unsigned short As[64 * PSTR];
  __shared__ unsigned short Bs[128 * PSTR];
  const int tid = threadIdx.x;
  const int lane = tid & 63;
  const int wid = tid >> 6;
  const int wr = wid >> 1, wc = wid & 1;
  const int lo = lane & 31, hi = lane >> 5;

  // XCD swizzle: xcd = bid&7; 16 m-tiles per XCD, nt inner
  int bid = blockIdx.x;
  int r = bid >> 3;
  int mt = (bid & 7) * 16 + (r & 15);
  int nt = r >> 4;                      // 0..1
  const int m0 = mt * 64;
  const int n0 = nt * 128;

  const int arow = tid >> 2;            // 0..63
  const int ag0 = (tid & 3) * 2;        // granules {ag0, ag0+1}
  const int brow = tid >> 1;            // 0..127
  const int bg0 = (tid & 1) * 4;        // granules bg0..bg0+4

  short8 raA[2];
  float4 raB[8];
  f32x16 acc[2];
#pragma unroll
  for (int a = 0; a < 2; ++a)
#pragma unroll
    for (int q = 0; q < 16; ++q) acc[a][q] = 0.f;

  // prologue load k0=0
#pragma unroll
  for (int j = 0; j < 2; ++j)
    raA[j] = *reinterpret_cast<const short8*>(&ao[(size_t)(m0 + arow) * HE + (ag0 + j) * 8]);
#pragma unroll
  for (int g = 0; g < 4; ++g) {
    raB[2 * g]     = *reinterpret_cast<const float4*>(&Wu[(size_t)(n0 + brow) * HE + (bg0 + g) * 8]);
    raB[2 * g + 1] = *reinterpret_cast<const float4*>(&Wu[(size_t)(n0 + brow) * HE + (bg0 + g) * 8 + 4]);
  }

  for (int t = 0; t < 32; ++t) {
#pragma unroll
    for (int j = 0; j < 2; ++j)
      *reinterpret_cast<short8*>(&As[arow * PSTR + (ag0 + j) * 8]) = raA[j];
#pragma unroll
    for (int g = 0; g < 4; ++g) {
      union { unsigned int u[4]; short8 v; } w;
      w.u[0] = pk_bf16(raB[2 * g].x, raB[2 * g].y);
      w.u[1] = pk_bf16(raB[2 * g].z, raB[2 * g].w);
      w.u[2] = pk_bf16(raB[2 * g + 1].x, raB[2 * g + 1].y);
      w.u[3] = pk_bf16(raB[2 * g + 1].z, raB[2 * g + 1].w);
      *reinterpret_cast<short8*>(&Bs[brow * PSTR + (bg0 + g) * 8]) = w.v;
    }
    asm volatile("s_waitcnt lgkmcnt(0)" ::: "memory");
    __builtin_amdgcn_s_barrier();
    __builtin_amdgcn_sched_barrier(0);

    if (t + 1 < 32) {
      int k0 = (t + 1) * 64;
#pragma unroll
      for (int j = 0; j < 2; ++j)
        raA[j] = *reinterpret_cast<const short8*>(&ao[(size_t)(m0 + arow) * HE + k0 + (ag0 + j) * 8]);
#pragma unroll
      for (int g = 0; g < 4; ++g) {
        raB[2 * g]     = *reinterpret_cast<const float4*>(&Wu[(size_t)(n0 + brow) * HE + k0 + (bg0 + g) * 8]);
        raB[2 * g + 1] = *reinterpret_cast<const float4*>(&Wu[(size_t)(n0 + brow) * HE + k0 + (bg0 + g) * 8 + 4]);
      }
    }

    __builtin_amdgcn_s_setprio(1);
#pragma unroll
    for (int ks = 0; ks < 4; ++ks) {
      short8 af = *reinterpret_cast<const short8*>(&As[(32 * wr + lo) * PSTR + ks * 16 + hi * 8]);
#pragma unroll
      for (int ni = 0; ni < 2; ++ni) {
        short8 bf = *reinterpret_cast<const short8*>(&Bs[(64 * wc + 32 * ni + lo) * PSTR + ks * 16 + hi * 8]);
        acc[ni] = __builtin_amdgcn_mfma_f32_32x32x16_bf16(af, bf, acc[ni], 0, 0, 0);
      }
    }
    __builtin_amdgcn_s_setprio(0);
    __builtin_amdgcn_s_barrier();
    __builtin_amdgcn_sched_barrier(0);
  }

  // epilogue: += x2 + bias, f32 out
#pragma unroll
  for (int ni = 0; ni < 2; ++ni) {
    int n = n0 + 64 * wc + 32 * ni + lo;
    float bias = bu[n];
#pragma unroll
    for (int q = 0; q < 16; ++q) {
      int rr = (q & 3) + 8 * (q >> 2) + 4 * hi;
      int m = m0 + 32 * wr + rr;
      float o = acc[ni][q] + x[(size_t)m * CC + EE + n] + bias;
      out[(size_t)m * CC + EE + n] = o;
    }
  }
}

// ---------------------------------------------------------------------------
extern "C" void kernel_launch(void* const* d_in, const int* in_sizes, int n_in,
                              void* d_out, int out_size, void* d_ws, size_t ws_size,
                              hipStream_t stream) {
  const float* x  = (const float*)d_in[0];
  const float* Wq = (const float*)d_in[1];
  const float* Wk = (const float*)d_in[2];
  const float* Wv = (const float*)d_in[3];
  const float* Wu = (const float*)d_in[4];
  const float* bu = (const float*)d_in[5];
  float* out = (float*)d_out;

  unsigned short* q  = (unsigned short*)d_ws;
  unsigned short* k  = q + (size_t)MM * HE;
  unsigned short* vt = k + (size_t)MM * HE;
  unsigned short* ao = vt + (size_t)MM * HE;

  qkv_fused_kernel<<<dim3(1024), dim3(512), 0, stream>>>(x, Wq, Wk, Wv, q, k, vt, out);

  attn_kernel<<<dim3(512), dim3(256), 0, stream>>>(q, k, vt, ao);

  proj_mfma_kernel<<<dim3(256), dim3(256), 0, stream>>>(ao, Wu, bu, x, out);
}

// Round 6
// 187.031 us; speedup vs baseline: 8.8200x; 1.0010x over previous
//
#include <hip/hip_runtime.h>
#include <hip/hip_bf16.h>

// Problem constants
#define BB 8
#define TT 1024
#define CC 512
#define HH 8
#define EE 256            // head dim (= C/2)
#define MM (BB*TT)        // 8192 rows
#define HE (HH*EE)        // 2048

using short8 = __attribute__((ext_vector_type(8))) short;
using f32x16 = __attribute__((ext_vector_type(16))) float;
using uint2v = __attribute__((ext_vector_type(2))) unsigned int;

__device__ __forceinline__ float bf2f(unsigned short u) {
  union { float f; unsigned int i; } v; v.i = ((unsigned int)u) << 16; return v.f;
}
__device__ __forceinline__ unsigned short f2bf(float f) {
  union { float f; unsigned int i; } v; v.f = f;
  unsigned int r = v.i + 0x7FFFu + ((v.i >> 16) & 1u);  // RNE
  return (unsigned short)(r >> 16);
}
__device__ __forceinline__ unsigned int pk_bf16(float lo, float hi) {
  unsigned int r;
  asm("v_cvt_pk_bf16_f32 %0, %1, %2" : "=v"(r) : "v"(lo), "v"(hi));
  return r;
}
// async global->LDS, 16B per lane; LDS dest = uniform base + lane*16
__device__ __forceinline__ void gll16(const void* g, void* l) {
  __builtin_amdgcn_global_load_lds(
      (const __attribute__((address_space(1))) unsigned int*)g,
      (__attribute__((address_space(3))) unsigned int*)l, 16, 0, 0);
}

// ---------------------------------------------------------------------------
// Kernel 1: FUSED QKV projection (MFMA) + x1 passthrough copy.
//   For w in {q,k,v}:  Cw[m][n] = scale_w * sum_k x[m][k] * Ww[n][k]
//   BM=BN=128, BK=64, 512 thr / 8 waves (2 wr x 4 wc), 4 K-iters, acc[3].
//   A staged once per iter (shared by all 3).  nt==0 blocks also store the
//   x1 tile (f32 regs they already loaded) to out cols 0..255 (copy fusion).
//   q scale folds log2(e) so attn can use exp2 directly.
//   V epilogue: LDS transpose -> vt[(b*8+h)*256+e][t] coalesced stores.
//   Grid 1024 1-D, mt-inner XCD swizzle: 8 m-tiles per XCD share B in L2.
// ---------------------------------------------------------------------------
#define FSTR 72
__global__ __launch_bounds__(512) void qkv_fused_kernel(const float* __restrict__ x,
                                                        const float* __restrict__ Wq,
                                                        const float* __restrict__ Wk,
                                                        const float* __restrict__ Wv,
                                                        unsigned short* __restrict__ outq,
                                                        unsigned short* __restrict__ outk,
                                                        unsigned short* __restrict__ outvt,
                                                        float* __restrict__ out) {
  __shared__ unsigned short smem[4 * 128 * FSTR];   // As, Bq, Bk, Bv  (73728 B)
  unsigned short* As = smem;
  unsigned short* Bs[3] = { smem + 128 * FSTR, smem + 2 * 128 * FSTR, smem + 3 * 128 * FSTR };

  const int tid = threadIdx.x;
  const int lane = tid & 63;
  const int wid = tid >> 6;
  const int wr = wid >> 2, wc = wid & 3;
  const int lo = lane & 31, hi = lane >> 5;

  // XCD swizzle: xcd = bid&7 owns m-tiles [xcd*8, xcd*8+8), mt-inner
  int bid = blockIdx.x;
  int r = bid >> 3;
  int mt = (bid & 7) * 8 + (r & 7);
  int nt = r >> 3;                      // 0..15
  const int m0 = mt * 128;
  const int n0 = nt * 128;

  const float* Wp[3] = { Wq, Wk, Wv };
  const float scl[3] = { 0.25f * 1.44269504089f, 0.25f, 1.0f };

  const int srow = tid >> 2;            // 0..127
  const int sc0 = (tid & 3) * 16;       // f32 col base (16 per thread)

  float4 ra[4], rb[3][4];
  f32x16 acc[3][2];
#pragma unroll
  for (int w = 0; w < 3; ++w)
#pragma unroll
    for (int mi = 0; mi < 2; ++mi)
#pragma unroll
      for (int q = 0; q < 16; ++q) acc[w][mi][q] = 0.f;

  // prologue loads (k0 = 0)
#pragma unroll
  for (int j = 0; j < 4; ++j)
    ra[j] = *reinterpret_cast<const float4*>(&x[(size_t)(m0 + srow) * CC + sc0 + 4 * j]);
#pragma unroll
  for (int w = 0; w < 3; ++w)
#pragma unroll
    for (int j = 0; j < 4; ++j)
      rb[w][j] = *reinterpret_cast<const float4*>(&Wp[w][(size_t)(n0 + srow) * EE + sc0 + 4 * j]);

  for (int t = 0; t < 4; ++t) {
    // cvt + ds_write current regs
    {
      union { unsigned int u[4]; short8 v; } p0, p1;
      p0.u[0] = pk_bf16(ra[0].x, ra[0].y); p0.u[1] = pk_bf16(ra[0].z, ra[0].w);
      p0.u[2] = pk_bf16(ra[1].x, ra[1].y); p0.u[3] = pk_bf16(ra[1].z, ra[1].w);
      p1.u[0] = pk_bf16(ra[2].x, ra[2].y); p1.u[1] = pk_bf16(ra[2].z, ra[2].w);
      p1.u[2] = pk_bf16(ra[3].x, ra[3].y); p1.u[3] = pk_bf16(ra[3].z, ra[3].w);
      *reinterpret_cast<short8*>(&As[srow * FSTR + sc0]) = p0.v;
      *reinterpret_cast<short8*>(&As[srow * FSTR + sc0 + 8]) = p1.v;
#pragma unroll
      for (int w = 0; w < 3; ++w) {
        union { unsigned int u[4]; short8 v; } q0, q1;
        q0.u[0] = pk_bf16(rb[w][0].x, rb[w][0].y); q0.u[1] = pk_bf16(rb[w][0].z, rb[w][0].w);
        q0.u[2] = pk_bf16(rb[w][1].x, rb[w][1].y); q0.u[3] = pk_bf16(rb[w][1].z, rb[w][1].w);
        q1.u[0] = pk_bf16(rb[w][2].x, rb[w][2].y); q1.u[1] = pk_bf16(rb[w][2].z, rb[w][2].w);
        q1.u[2] = pk_bf16(rb[w][3].x, rb[w][3].y); q1.u[3] = pk_bf16(rb[w][3].z, rb[w][3].w);
        *reinterpret_cast<short8*>(&Bs[w][srow * FSTR + sc0]) = q0.v;
        *reinterpret_cast<short8*>(&Bs[w][srow * FSTR + sc0 + 8]) = q1.v;
      }
    }
    // fused x1 copy: nt==0 blocks store the x-tile slice (still in ra)
    if (n0 == 0) {
      int k0 = t * 64;
#pragma unroll
      for (int j = 0; j < 4; ++j)
        *reinterpret_cast<float4*>(&out[(size_t)(m0 + srow) * CC + k0 + sc0 + 4 * j]) = ra[j];
    }
    asm volatile("s_waitcnt lgkmcnt(0)" ::: "memory");
    __builtin_amdgcn_s_barrier();
    __builtin_amdgcn_sched_barrier(0);

    if (t + 1 < 4) {
      int k0 = (t + 1) * 64;
#pragma unroll
      for (int j = 0; j < 4; ++j)
        ra[j] = *reinterpret_cast<const float4*>(&x[(size_t)(m0 + srow) * CC + k0 + sc0 + 4 * j]);
#pragma unroll
      for (int w = 0; w < 3; ++w)
#pragma unroll
        for (int j = 0; j < 4; ++j)
          rb[w][j] = *reinterpret_cast<const float4*>(&Wp[w][(size_t)(n0 + srow) * EE + k0 + sc0 + 4 * j]);
    }

    __builtin_amdgcn_s_setprio(1);
#pragma unroll
    for (int ks = 0; ks < 4; ++ks) {
      short8 af[2];
#pragma unroll
      for (int mi = 0; mi < 2; ++mi)
        af[mi] = *reinterpret_cast<const short8*>(&As[(64 * wr + 32 * mi + lo) * FSTR + ks * 16 + hi * 8]);
#pragma unroll
      for (int w = 0; w < 3; ++w) {
        short8 bf = *reinterpret_cast<const short8*>(&Bs[w][(32 * wc + lo) * FSTR + ks * 16 + hi * 8]);
#pragma unroll
        for (int mi = 0; mi < 2; ++mi)
          acc[w][mi] = __builtin_amdgcn_mfma_f32_32x32x16_bf16(af[mi], bf, acc[w][mi], 0, 0, 0);
      }
    }
    __builtin_amdgcn_s_setprio(0);
    __builtin_amdgcn_s_barrier();
    __builtin_amdgcn_sched_barrier(0);
  }

  // ---- epilogue: q, k direct coalesced stores
#pragma unroll
  for (int w = 0; w < 2; ++w) {
    unsigned short* op = (w == 0) ? outq : outk;
#pragma unroll
    for (int mi = 0; mi < 2; ++mi) {
#pragma unroll
      for (int q = 0; q < 16; ++q) {
        int rr = (q & 3) + 8 * (q >> 2) + 4 * hi;
        int m = m0 + 64 * wr + 32 * mi + rr;
        int n = n0 + 32 * wc + lo;
        op[(size_t)m * HE + n] = f2bf(acc[w][mi][q] * scl[w]);
      }
    }
  }

  // ---- V: LDS transpose then coalesced vt stores
  unsigned short* Tr = smem;            // [128 n][136] m-major rows
  __syncthreads();                      // everyone done with As/Bs
#pragma unroll
  for (int mi = 0; mi < 2; ++mi)
#pragma unroll
    for (int q = 0; q < 16; ++q) {
      int rr = (q & 3) + 8 * (q >> 2) + 4 * hi;
      Tr[(32 * wc + lo) * 136 + 64 * wr + 32 * mi + rr] = f2bf(acc[2][mi][q]);
    }
  __syncthreads();
  {
    const int b = m0 >> 10;
    const int t0m = m0 & 1023;
#pragma unroll
    for (int p = 0; p < 4; ++p) {
      int nr = p * 32 + (tid >> 4);
      int chunk = tid & 15;
      int n = n0 + nr;
      size_t drow = ((size_t)b * 8 + (n >> 8)) * 256 + (n & 255);
      *reinterpret_cast<short8*>(&outvt[drow * TT + t0m + chunk * 8]) =
          *reinterpret_cast<const short8*>(&Tr[nr * 136 + chunk * 8]);
    }
  }
}

// ---------------------------------------------------------------------------
// Kernel 2: pipelined MFMA attention.
//   256 thr = 4 waves, each wave owns 32 q-rows (QBLK=128), SBLK=32,
//   32 K/V tiles, no s-split.  K[32][256] + Vt[256][32] double-buffered.
//   global_load_lds staging with XOR-granule pre-swizzle on global source.
//   Main loop: stage(t+1, other buf) -> compute(t) -> vmcnt(0)+barrier.
//   Softmax = exp2 (log2e folded into q scale), P packed in-register via
//   v_cvt_pk_bf16_f32 + permlane32_swap.  setprio around MFMA clusters.
// ---------------------------------------------------------------------------
#define SBLK 32
__global__ __launch_bounds__(256, 2) void attn_kernel(const unsigned short* __restrict__ qg,
                                                      const unsigned short* __restrict__ kg,
                                                      const unsigned short* __restrict__ vtg,
                                                      unsigned short* __restrict__ og) {
  __shared__ char smem[66048];
  unsigned short* Kbuf = (unsigned short*)smem;              // 2 x [32][256]
  unsigned short* Vbuf = (unsigned short*)(smem + 32768);    // 2 x [256][32]
  float* lpart = (float*)(smem + 65536);                     // [128]

  const int tid = threadIdx.x;
  const int lane = tid & 63;
  const int wid = tid >> 6;           // 0..3: q-subtile
  const int lo = lane & 31, hi = lane >> 5;

  // XCD-aware bijective swizzle: 8 t-tiles of each (b,h) stay on one XCD
  int logical = (blockIdx.x & 7) * 64 + (blockIdx.x >> 3);
  const int bh = logical >> 3;
  const int t0 = (logical & 7) * 128;
  const int b = bh >> 3, h = bh & 7;
  const size_t qkbase = (size_t)b * TT * HE + (size_t)h * EE;
  const size_t vtbase = (size_t)bh * EE * TT;
  const unsigned short* kg_base = kg + qkbase;
  const unsigned short* vt_base = vtg + vtbase;

  // hoist Q fragments (B-operand): lane holds q-row t0+32*wid+lo
  short8 qf[16];
  {
    const unsigned short* qrow = qg + qkbase + (size_t)(t0 + 32 * wid + lo) * HE + hi * 8;
#pragma unroll
    for (int ks = 0; ks < 16; ++ks)
      qf[ks] = *reinterpret_cast<const short8*>(qrow + ks * 16);
  }

  f32x16 Oacc[8];
#pragma unroll
  for (int et = 0; et < 8; ++et)
#pragma unroll
    for (int q = 0; q < 16; ++q) Oacc[et][q] = 0.f;
  float lacc = 0.f;

  // staging lane decomposition
  const int k_sub = lane >> 5;        // K: 2 rows / instr
  const int k_g   = lane & 31;
  const int v_er  = lane >> 2;        // V: 16 rows / instr
  const int v_g   = lane & 3;
  const int v_gs  = v_g ^ ((lane >> 3) & 3);

#define STAGE_TILE(TIDX, BUF)                                                        \
  {                                                                                  \
    const unsigned short* kt = kg_base + (size_t)(TIDX) * SBLK * HE;                 \
    const unsigned short* vt = vt_base + (size_t)(TIDX) * SBLK;                      \
    unsigned short* Kb = Kbuf + (BUF) * (SBLK * 256);                                \
    unsigned short* Vb = Vbuf + (BUF) * (256 * SBLK);                                \
    _Pragma("unroll")                                                                \
    for (int i = 0; i < 4; ++i) {                                                    \
      int row = 8 * wid + 2 * i + k_sub;                                             \
      int gs = k_g ^ (row & 7);                                                      \
      gll16(kt + (size_t)row * HE + gs * 8, Kb + (8 * wid + 2 * i) * 256);           \
    }                                                                                \
    _Pragma("unroll")                                                                \
    for (int i = 0; i < 4; ++i) {                                                    \
      int row = 64 * wid + 16 * i + v_er;                                            \
      gll16(vt + (size_t)row * TT + v_gs * 8, Vb + (64 * wid + 16 * i) * SBLK);      \
    }                                                                                \
  }

  STAGE_TILE(0, 0)
  asm volatile("s_waitcnt vmcnt(0)" ::: "memory");
  __builtin_amdgcn_s_barrier();
  __builtin_amdgcn_sched_barrier(0);

  for (int t = 0; t < 32; ++t) {
    const int cur = t & 1;
    if (t + 1 < 32) STAGE_TILE(t + 1, cur ^ 1)

    const unsigned short* Kb = Kbuf + cur * (SBLK * 256);
    const unsigned short* Vb = Vbuf + cur * (256 * SBLK);

    // ---- QK^T (swapped): S^T[32 s x 32 q]
    f32x16 sacc;
#pragma unroll
    for (int q = 0; q < 16; ++q) sacc[q] = 0.f;
    const int sxor = lo & 7;
    __builtin_amdgcn_s_setprio(1);
#pragma unroll
    for (int ks = 0; ks < 16; ++ks) {
      int slot = (ks * 2 + hi) ^ sxor;
      short8 kf = *reinterpret_cast<const short8*>(&Kb[lo * 256 + slot * 8]);
      sacc = __builtin_amdgcn_mfma_f32_32x32x16_bf16(kf, qf[ks], sacc, 0, 0, 0);
    }
    __builtin_amdgcn_s_setprio(0);

    // ---- softmax numerator (exp2; log2e pre-folded) + pack to A-frags
    short8 pa[2];
#pragma unroll
    for (int ksl = 0; ksl < 2; ++ksl) {
      float p0 = __builtin_amdgcn_exp2f(sacc[8 * ksl + 0]);
      float p1 = __builtin_amdgcn_exp2f(sacc[8 * ksl + 1]);
      float p2 = __builtin_amdgcn_exp2f(sacc[8 * ksl + 2]);
      float p3 = __builtin_amdgcn_exp2f(sacc[8 * ksl + 3]);
      float p4 = __builtin_amdgcn_exp2f(sacc[8 * ksl + 4]);
      float p5 = __builtin_amdgcn_exp2f(sacc[8 * ksl + 5]);
      float p6 = __builtin_amdgcn_exp2f(sacc[8 * ksl + 6]);
      float p7 = __builtin_amdgcn_exp2f(sacc[8 * ksl + 7]);
      lacc += ((p0 + p1) + (p2 + p3)) + ((p4 + p5) + (p6 + p7));
      unsigned int a1 = pk_bf16(p0, p1), a2 = pk_bf16(p2, p3);
      unsigned int b1 = pk_bf16(p4, p5), b2 = pk_bf16(p6, p7);
      uint2v r1 = __builtin_amdgcn_permlane32_swap(a1, b1, false, false);
      uint2v r2 = __builtin_amdgcn_permlane32_swap(a2, b2, false, false);
      union { unsigned int u[4]; short8 v; } uu;
      uu.u[0] = r1[0]; uu.u[1] = r2[0]; uu.u[2] = r1[1]; uu.u[3] = r2[1];
      pa[ksl] = uu.v;
    }

    // ---- PV: O[32q][256e] += P[32q][32s] * V[32s][256e]
    const int vxor = (lo >> 1) & 3;
    __builtin_amdgcn_s_setprio(1);
#pragma unroll
    for (int et = 0; et < 8; ++et) {
      const int erow = et * 32 + lo;
#pragma unroll
      for (int ksl = 0; ksl < 2; ++ksl) {
        int slot = (2 * ksl + hi) ^ vxor;
        short8 vf = *reinterpret_cast<const short8*>(&Vb[erow * SBLK + slot * 8]);
        Oacc[et] = __builtin_amdgcn_mfma_f32_32x32x16_bf16(pa[ksl], vf, Oacc[et], 0, 0, 0);
      }
    }
    __builtin_amdgcn_s_setprio(0);

    asm volatile("s_waitcnt vmcnt(0)" ::: "memory");
    __builtin_amdgcn_s_barrier();
    __builtin_amdgcn_sched_barrier(0);
  }

  // ---- epilogue: fold hi halves of lacc, redistribute by q-row, store
  lacc += __shfl_xor(lacc, 32);
  if (hi == 0) lpart[wid * 32 + lo] = lacc;
  __syncthreads();
#pragma unroll
  for (int q = 0; q < 16; ++q) {
    int rr = (q & 3) + 8 * (q >> 2) + 4 * hi;
    float inv = 1.0f / lpart[wid * 32 + rr];
    int tq = t0 + 32 * wid + rr;
#pragma unroll
    for (int et = 0; et < 8; ++et)
      og[qkbase + (size_t)tq * HE + et * 32 + lo] = f2bf(Oacc[et][q] * inv);
  }
#undef STAGE_TILE
}

// ---------------------------------------------------------------------------
// Kernel 3: output projection (MFMA) + bias + residual into out cols 256..511
//   A = ao bf16 [8192][2048], B = Wu f32 [256][2048].
//   BM=64, BN=128, BK=64, 256 thr / 4 waves, 32 K-iters.
//   1-D grid 256 with XCD swizzle: each XCD keeps the whole 2MB Wu in L2.
// ---------------------------------------------------------------------------
#define PSTR 72
__global__ __launch_bounds__(256) void proj_mfma_kernel(const unsigned short* __restrict__ ao,
                                                        const float* __restrict__ Wu,
                                                        const float* __restrict__ bu,
                                                        const float* __restrict__ x,
                                                        float* __restrict__ out) {
  __shared__ unsigned short As[64 * PSTR];
  __shared__ unsigned short Bs[128 * PSTR];
  const int tid = threadIdx.x;
  const int lane = tid & 63;
  const int wid = tid >> 6;
  const int wr = wid >> 1, wc = wid & 1;
  const int lo = lane & 31, hi = lane >> 5;

  // XCD swizzle: xcd = bid&7; 16 m-tiles per XCD, nt inner
  int bid = blockIdx.x;
  int r = bid >> 3;
  int mt = (bid & 7) * 16 + (r & 15);
  int nt = r >> 4;                      // 0..1
  const int m0 = mt * 64;
  const int n0 = nt * 128;

  const int arow = tid >> 2;            // 0..63
  const int ag0 = (tid & 3) * 2;        // granules {ag0, ag0+1}
  const int brow = tid >> 1;            // 0..127
  const int bg0 = (tid & 1) * 4;        // granules bg0..bg0+4

  short8 raA[2];
  float4 raB[8];
  f32x16 acc[2];
#pragma unroll
  for (int a = 0; a < 2; ++a)
#pragma unroll
    for (int q = 0; q < 16; ++q) acc[a][q] = 0.f;

  // prologue load k0=0
#pragma unroll
  for (int j = 0; j < 2; ++j)
    raA[j] = *reinterpret_cast<const short8*>(&ao[(size_t)(m0 + arow) * HE + (ag0 + j) * 8]);
#pragma unroll
  for (int g = 0; g < 4; ++g) {
    raB[2 * g]     = *reinterpret_cast<const float4*>(&Wu[(size_t)(n0 + brow) * HE + (bg0 + g) * 8]);
    raB[2 * g + 1] = *reinterpret_cast<const float4*>(&Wu[(size_t)(n0 + brow) * HE + (bg0 + g) * 8 + 4]);
  }

  for (int t = 0; t < 32; ++t) {
#pragma unroll
    for (int j = 0; j < 2; ++j)
      *reinterpret_cast<short8*>(&As[arow * PSTR + (ag0 + j) * 8]) = raA[j];
#pragma unroll
    for (int g = 0; g < 4; ++g) {
      union { unsigned int u[4]; short8 v; } w;
      w.u[0] = pk_bf16(raB[2 * g].x, raB[2 * g].y);
      w.u[1] = pk_bf16(raB[2 * g].z, raB[2 * g].w);
      w.u[2] = pk_bf16(raB[2 * g + 1].x, raB[2 * g + 1].y);
      w.u[3] = pk_bf16(raB[2 * g + 1].z, raB[2 * g + 1].w);
      *reinterpret_cast<short8*>(&Bs[brow * PSTR + (bg0 + g) * 8]) = w.v;
    }
    asm volatile("s_waitcnt lgkmcnt(0)" ::: "memory");
    __builtin_amdgcn_s_barrier();
    __builtin_amdgcn_sched_barrier(0);

    if (t + 1 < 32) {
      int k0 = (t + 1) * 64;
#pragma unroll
      for (int j = 0; j < 2; ++j)
        raA[j] = *reinterpret_cast<const short8*>(&ao[(size_t)(m0 + arow) * HE + k0 + (ag0 + j) * 8]);
#pragma unroll
      for (int g = 0; g < 4; ++g) {
        raB[2 * g]     = *reinterpret_cast<const float4*>(&Wu[(size_t)(n0 + brow) * HE + k0 + (bg0 + g) * 8]);
        raB[2 * g + 1] = *reinterpret_cast<const float4*>(&Wu[(size_t)(n0 + brow) * HE + k0 + (bg0 + g) * 8 + 4]);
      }
    }

    __builtin_amdgcn_s_setprio(1);
#pragma unroll
    for (int ks = 0; ks < 4; ++ks) {
      short8 af = *reinterpret_cast<const short8*>(&As[(32 * wr + lo) * PSTR + ks * 16 + hi * 8]);
#pragma unroll
      for (int ni = 0; ni < 2; ++ni) {
        short8 bf = *reinterpret_cast<const short8*>(&Bs[(64 * wc + 32 * ni + lo) * PSTR + ks * 16 + hi * 8]);
        acc[ni] = __builtin_amdgcn_mfma_f32_32x32x16_bf16(af, bf, acc[ni], 0, 0, 0);
      }
    }
    __builtin_amdgcn_s_setprio(0);
    __builtin_amdgcn_s_barrier();
    __builtin_amdgcn_sched_barrier(0);
  }

  // epilogue: += x2 + bias, f32 out
#pragma unroll
  for (int ni = 0; ni < 2; ++ni) {
    int n = n0 + 64 * wc + 32 * ni + lo;
    float bias = bu[n];
#pragma unroll
    for (int q = 0; q < 16; ++q) {
      int rr = (q & 3) + 8 * (q >> 2) + 4 * hi;
      int m = m0 + 32 * wr + rr;
      float o = acc[ni][q] + x[(size_t)m * CC + EE + n] + bias;
      out[(size_t)m * CC + EE + n] = o;
    }
  }
}

// ---------------------------------------------------------------------------
extern "C" void kernel_launch(void* const* d_in, const int* in_sizes, int n_in,
                              void* d_out, int out_size, void* d_ws, size_t ws_size,
                              hipStream_t stream) {
  const float* x  = (const float*)d_in[0];
  const float* Wq = (const float*)d_in[1];
  const float* Wk = (const float*)d_in[2];
  const float* Wv = (const float*)d_in[3];
  const float* Wu = (const float*)d_in[4];
  const float* bu = (const float*)d_in[5];
  float* out = (float*)d_out;

  unsigned short* q  = (unsigned short*)d_ws;
  unsigned short* k  = q + (size_t)MM * HE;
  unsigned short* vt = k + (size_t)MM * HE;
  unsigned short* ao = vt + (size_t)MM * HE;

  qkv_fused_kernel<<<dim3(1024), dim3(512), 0, stream>>>(x, Wq, Wk, Wv, q, k, vt, out);

  attn_kernel<<<dim3(512), dim3(256), 0, stream>>>(q, k, vt, ao);

  proj_mfma_kernel<<<dim3(256), dim3(256), 0, stream>>>(ao, Wu, bu, x, out);
}